// Round 6
// baseline (6924.424 us; speedup 1.0000x reference)
//
#include <hip/hip_runtime.h>
#include <cstddef>

#define T_     8000
#define L_     803
#define C_     256
#define D_     512
#define NB_    32
#define FK_    20
#define NBATCH 4
#define EPS_   1e-5f

#define NBLK   208        // 52 groups (13 l-tiles x 4 batch) x 4 y-slices
#define NTHR   256
#define NTH_G  (NBLK * NTHR)

typedef __attribute__((ext_vector_type(8))) short bf16x8;
typedef __attribute__((ext_vector_type(4))) float f32x4;

__device__ __forceinline__ short f2bf(float x) {
  unsigned u = __float_as_uint(x);
  u += 0x7FFF + ((u >> 16) & 1);   // RNE
  return (short)(u >> 16);
}

// ---- device-scope barrier (sense-reversing, per-group) ----
struct __align__(64) Bar { unsigned cnt; unsigned phase; unsigned pad[14]; };

__device__ __forceinline__ void bar_sync(Bar* b, unsigned nblk, int tid) {
  __syncthreads();
  if (tid == 0) {
    __threadfence();   // device-scope release: L2 writeback
    unsigned ph = __hip_atomic_load(&b->phase, __ATOMIC_RELAXED, __HIP_MEMORY_SCOPE_AGENT);
    unsigned prev = __hip_atomic_fetch_add(&b->cnt, 1u, __ATOMIC_ACQ_REL, __HIP_MEMORY_SCOPE_AGENT);
    if (prev == nblk - 1) {
      __hip_atomic_store(&b->cnt, 0u, __ATOMIC_RELAXED, __HIP_MEMORY_SCOPE_AGENT);
      __hip_atomic_store(&b->phase, ph + 1u, __ATOMIC_RELEASE, __HIP_MEMORY_SCOPE_AGENT);
    } else {
      while (__hip_atomic_load(&b->phase, __ATOMIC_ACQUIRE, __HIP_MEMORY_SCOPE_AGENT) == ph)
        __builtin_amdgcn_s_sleep(2);
    }
    __threadfence();   // acquire side: invalidate stale L1/L2
  }
  __syncthreads();
}

struct KParams {
  const float *x, *w_enc, *w1, *wd, *w2, *w_dec;
  const float *g1, *bb1, *m1, *v1;
  const float *g2, *bb2, *m2, *v2;
  const float *g3, *bb3, *m3, *v3;
  float *out;
  float *xe, *h, *z;
  float *s1, *o1, *s2, *o2, *s3, *o3;
  short *w1b, *w2b;
  Bar *bars;     // [0]=global, [1+n]=per-batch-n (52 blocks each)
};

__global__ __launch_bounds__(NTHR) void tasnet_persistent(KParams p) {
  const int tid = threadIdx.x;
  const int bid = blockIdx.x;
  const int gtid = bid * NTHR + tid;

  // block geometry: group g = (x,n) l-tile+batch; y = slice
  const int g = bid >> 2, y = bid & 3;
  const int xt = g % 13, n = g / 13;
  const int l0 = xt * 64;

  Bar* gbar = p.bars;
  Bar* nbar = p.bars + 1 + n;

  __shared__ __align__(16) short Bs[64][264];            // B tile [col][k], 33KB
  __shared__ float s1L[C_], b1L[C_];
  __shared__ float w0L[D_], w1L[D_], w2L[D_], s3L[D_], b3L[D_];

  // ---------------- phase 0: BN fold + weight cvt + encoder ----------------
  for (int i = gtid; i < NB_ * C_; i += NTH_G) {
    float s = p.g1[i] * rsqrtf(p.v1[i] + EPS_);
    p.s1[i] = s; p.o1[i] = p.bb1[i] - p.m1[i] * s;
  }
  for (int i = gtid; i < NB_ * D_; i += NTH_G) {
    float s2 = p.g2[i] * rsqrtf(p.v2[i] + EPS_);
    p.s2[i] = s2; p.o2[i] = p.bb2[i] - p.m2[i] * s2;
    float s3 = p.g3[i] * rsqrtf(p.v3[i] + EPS_);
    p.s3[i] = s3; p.o3[i] = p.bb3[i] - p.m3[i] * s3;
  }
  for (int i = gtid; i < NB_ * D_ * C_; i += NTH_G) {
    p.w1b[i] = f2bf(p.w1[i]);
    p.w2b[i] = f2bf(p.w2[i]);
  }
  for (int idx = gtid; idx < NBATCH * C_ * L_; idx += NTH_G) {
    int l = idx % L_;
    int c = (idx / L_) % C_;
    int nn = idx / (L_ * C_);
    const float* xn = p.x + (size_t)nn * T_;
    const float* w = p.w_enc + c * FK_;
    int t0 = l * 10 - 20;
    float acc = 0.f;
#pragma unroll
    for (int k = 0; k < FK_; k++) {
      int t = t0 + k;
      float xv = (t >= 0 && t < T_) ? xn[t] : 0.f;
      acc = fmaf(xv, w[k], acc);
    }
    p.xe[idx] = acc;
    p.h[idx] = acc;
  }
  bar_sync(gbar, NBLK, tid);

  // thread roles (shared by both stages)
  const int col = tid & 63, kc = (tid >> 6) * 8;   // staging: col + 8-k slice
  const int lB = l0 + col;
  const bool lv = lB < L_;
  const int wv = tid >> 6, lane = tid & 63;
  const int wr = wv >> 1, wc = wv & 1;
  const int frow = lane & 15, kg = lane >> 4;
  const float* hn = p.h + (size_t)n * (C_ * L_);
  float* hw = p.h + (size_t)n * (C_ * L_);
  const float* znr = p.z + (size_t)n * (D_ * L_);
  float* znw = p.z + (size_t)n * (D_ * L_);

  // ---------------- 32 residual blocks ----------------
  for (int layer = 0; layer < NB_; ++layer) {
    const int dil = 1 << (layer & 7);

    // ===== stage1: z = BN2( W1 @ BN1(h) ) ; tile d:[y*128,+128) x l:[l0,+64)
    {
      const short* W = p.w1b + (size_t)layer * D_ * C_;
      const int d0 = y * 128;
      s1L[tid] = p.s1[layer * C_ + tid];
      b1L[tid] = p.o1[layer * C_ + tid];
      __syncthreads();
      // B staging: full K=256
#pragma unroll
      for (int it = 0; it < 8; ++it) {
        int k = it * 32 + kc;
        bf16x8 pb;
#pragma unroll
        for (int q = 0; q < 8; ++q) {
          float v = lv ? hn[(size_t)(k + q) * L_ + lB] : 0.f;
          pb[q] = f2bf(fmaf(v, s1L[k + q], b1L[k + q]));
        }
        *(bf16x8*)&Bs[col][k] = pb;
      }
      __syncthreads();
      // MFMA: wave tile 64(d) x 32(l); A direct from global bf16
      f32x4 acc[4][2] = {};
      const short* Wb = W + (size_t)(d0 + wr * 64 + frow) * C_;
#pragma unroll
      for (int k0 = 0; k0 < 8; ++k0) {
        int kb = k0 * 32 + kg * 8;
        bf16x8 b0 = *(bf16x8*)&Bs[wc * 32 + frow][kb];
        bf16x8 b1 = *(bf16x8*)&Bs[wc * 32 + 16 + frow][kb];
#pragma unroll
        for (int ia = 0; ia < 4; ++ia) {
          bf16x8 af = *(const bf16x8*)(Wb + (size_t)ia * 16 * C_ + kb);
          acc[ia][0] = __builtin_amdgcn_mfma_f32_16x16x32_bf16(af, b0, acc[ia][0], 0, 0, 0);
          acc[ia][1] = __builtin_amdgcn_mfma_f32_16x16x32_bf16(af, b1, acc[ia][1], 0, 0, 0);
        }
      }
      // epilogue: z = acc*s2 + b2
#pragma unroll
      for (int ia = 0; ia < 4; ++ia) {
        int dbase = d0 + wr * 64 + ia * 16 + kg * 4;
#pragma unroll
        for (int jj = 0; jj < 4; ++jj) {
          int d = dbase + jj;
          float sc = p.s2[layer * D_ + d], bi = p.o2[layer * D_ + d];
#pragma unroll
          for (int jb = 0; jb < 2; ++jb) {
            int l = l0 + wc * 32 + jb * 16 + frow;
            if (l < L_) znw[(size_t)d * L_ + l] = fmaf(acc[ia][jb][jj], sc, bi);
          }
        }
      }
    }
    bar_sync(nbar, 52, tid);

    // ===== stage2: h += W2 @ BN3(dconv(z)) ; tile c:[y*64,+64) x l:[l0,+64)
    {
      const short* W = p.w2b + (size_t)layer * C_ * D_;
      const int c0 = y * 64;
      const float* wdi = p.wd + (size_t)layer * D_ * 3;
#pragma unroll
      for (int i = tid; i < D_; i += NTHR) {
        w0L[i] = wdi[3 * i];
        w1L[i] = wdi[3 * i + 1];
        w2L[i] = wdi[3 * i + 2];
        s3L[i] = p.s3[layer * D_ + i];
        b3L[i] = p.o3[layer * D_ + i];
      }
      const bool lvm = lv && (lB >= dil);
      const bool lvp = lv && (lB + dil < L_);
      f32x4 acc[2][2] = {};
#pragma unroll
      for (int half = 0; half < 2; ++half) {
        const int kh = half * 256;
        __syncthreads();   // params ready / prev-half MFMA reads done
#pragma unroll
        for (int it = 0; it < 8; ++it) {
          int krel = it * 32 + kc;
          int d = kh + krel;
          bf16x8 pb;
#pragma unroll
          for (int q = 0; q < 8; ++q) {
            const float* zd = znr + (size_t)(d + q) * L_;
            float m = 0.f;
            if (lv)  m = zd[lB] * w1L[d + q];
            if (lvm) m = fmaf(zd[lB - dil], w0L[d + q], m);
            if (lvp) m = fmaf(zd[lB + dil], w2L[d + q], m);
            pb[q] = f2bf(fmaf(m, s3L[d + q], b3L[d + q]));
          }
          *(bf16x8*)&Bs[col][krel] = pb;
        }
        __syncthreads();
        // MFMA: wave tile 32(c) x 32(l)
        const short* Wb = W + (size_t)(c0 + wr * 32 + frow) * D_ + kh;
#pragma unroll
        for (int k0 = 0; k0 < 8; ++k0) {
          int kb = k0 * 32 + kg * 8;
          bf16x8 b0 = *(bf16x8*)&Bs[wc * 32 + frow][kb];
          bf16x8 b1 = *(bf16x8*)&Bs[wc * 32 + 16 + frow][kb];
#pragma unroll
          for (int ia = 0; ia < 2; ++ia) {
            bf16x8 af = *(const bf16x8*)(Wb + (size_t)ia * 16 * D_ + kb);
            acc[ia][0] = __builtin_amdgcn_mfma_f32_16x16x32_bf16(af, b0, acc[ia][0], 0, 0, 0);
            acc[ia][1] = __builtin_amdgcn_mfma_f32_16x16x32_bf16(af, b1, acc[ia][1], 0, 0, 0);
          }
        }
      }
      // epilogue: h +=
#pragma unroll
      for (int ia = 0; ia < 2; ++ia) {
        int cbase = c0 + wr * 32 + ia * 16 + kg * 4;
#pragma unroll
        for (int jj = 0; jj < 4; ++jj) {
          int c = cbase + jj;
#pragma unroll
          for (int jb = 0; jb < 2; ++jb) {
            int l = l0 + wc * 32 + jb * 16 + frow;
            if (l < L_) hw[(size_t)c * L_ + l] += acc[ia][jb][jj];
          }
        }
      }
    }
    bar_sync(nbar, 52, tid);
  }

  bar_sync(gbar, NBLK, tid);

  // ---------------- mask: y = xe * sigmoid(h)  (y reuses z) ----------------
  for (int idx = gtid; idx < NBATCH * C_ * L_; idx += NTH_G) {
    float hv = p.h[idx];
    p.z[idx] = p.xe[idx] / (1.f + expf(-hv));
  }
  bar_sync(gbar, NBLK, tid);

  // ---------------- decoder ----------------
  for (int idx = gtid; idx < NBATCH * T_; idx += NTH_G) {
    int t = idx % T_;
    int nn = idx / T_;
    int tt = t + FK_;
    int lq = tt / 10;      // in [2, 801]
    int k0 = tt % 10;
    const float* yn = p.z + (size_t)nn * C_ * L_;
    float acc = 0.f;
#pragma unroll 8
    for (int c = 0; c < C_; c++) {
      const float* yr = yn + (size_t)c * L_;
      const float* wr2 = p.w_dec + c * FK_;
      acc = fmaf(yr[lq], wr2[k0], acc);
      acc = fmaf(yr[lq - 1], wr2[k0 + 10], acc);
    }
    p.out[idx] = acc;
  }
}

extern "C" void kernel_launch(void* const* d_in, const int* in_sizes, int n_in,
                              void* d_out, int out_size, void* d_ws, size_t ws_size,
                              hipStream_t stream) {
  const size_t NCL = (size_t)NBATCH * C_ * L_;      // 822272
  const size_t NDL = (size_t)NBATCH * D_ * L_;      // 1644544

  KParams hp;
  hp.x     = (const float*)d_in[0];
  hp.w_enc = (const float*)d_in[1];
  hp.w1    = (const float*)d_in[2];
  hp.wd    = (const float*)d_in[3];
  hp.w2    = (const float*)d_in[4];
  hp.w_dec = (const float*)d_in[5];
  hp.g1 = (const float*)d_in[6];  hp.bb1 = (const float*)d_in[7];
  hp.m1 = (const float*)d_in[8];  hp.v1  = (const float*)d_in[9];
  hp.g2 = (const float*)d_in[10]; hp.bb2 = (const float*)d_in[11];
  hp.m2 = (const float*)d_in[12]; hp.v2  = (const float*)d_in[13];
  hp.g3 = (const float*)d_in[14]; hp.bb3 = (const float*)d_in[15];
  hp.m3 = (const float*)d_in[16]; hp.v3  = (const float*)d_in[17];
  hp.out = (float*)d_out;

  // ws layout: [bars: 8*64B][floats...][bf16 weights]
  hp.bars = (Bar*)d_ws;
  float* cur = (float*)((char*)d_ws + 8 * sizeof(Bar));
  hp.xe = cur; cur += NCL;
  hp.h  = cur; cur += NCL;
  hp.z  = cur; cur += NDL;
  hp.s1 = cur; cur += NB_ * C_;
  hp.o1 = cur; cur += NB_ * C_;
  hp.s2 = cur; cur += NB_ * D_;
  hp.o2 = cur; cur += NB_ * D_;
  hp.s3 = cur; cur += NB_ * D_;
  hp.o3 = cur; cur += NB_ * D_;
  hp.w1b = (short*)cur;
  hp.w2b = hp.w1b + (size_t)NB_ * D_ * C_;

  // zero barrier state every call (deterministic; graph-capture legal)
  hipMemsetAsync(d_ws, 0, 8 * sizeof(Bar), stream);

  tasnet_persistent<<<dim3(NBLK), dim3(NTHR), 0, stream>>>(hp);
}

// Round 7
// 4334.697 us; speedup vs baseline: 1.5974x; 1.5974x over previous
//
#include <hip/hip_runtime.h>
#include <cstddef>

#define T_     8000
#define L_     803
#define C_     256
#define D_     512
#define NB_    32
#define FK_    20
#define NBATCH 4
#define EPS_   1e-5f

#define NBLK   208        // 52 groups (13 l-tiles x 4 batch) x 4 y-slices
#define NTHR   512        // 8 waves -> 2 waves/SIMD at 1 block/CU
#define NTH_G  (NBLK * NTHR)

typedef __attribute__((ext_vector_type(8))) short bf16x8;
typedef __attribute__((ext_vector_type(4))) short shortx4;
typedef __attribute__((ext_vector_type(4))) float f32x4;

__device__ __forceinline__ short f2bf(float x) {
  unsigned u = __float_as_uint(x);
  u += 0x7FFF + ((u >> 16) & 1);   // RNE
  return (short)(u >> 16);
}
__device__ __forceinline__ float bf2f(unsigned short u) {
  return __uint_as_float(((unsigned)u) << 16);
}

// ---- device-scope barrier: RELAXED spin, single acquire fence on exit ----
struct __align__(64) Bar { unsigned cnt; unsigned phase; unsigned pad[14]; };

__device__ __forceinline__ void bar_sync(Bar* b, unsigned nblk, int tid) {
  __syncthreads();
  if (tid == 0) {
    __threadfence();   // release: writeback own XCD L2
    unsigned ph = __hip_atomic_load(&b->phase, __ATOMIC_RELAXED, __HIP_MEMORY_SCOPE_AGENT);
    unsigned prev = __hip_atomic_fetch_add(&b->cnt, 1u, __ATOMIC_RELAXED, __HIP_MEMORY_SCOPE_AGENT);
    if (prev == nblk - 1) {
      __hip_atomic_store(&b->cnt, 0u, __ATOMIC_RELAXED, __HIP_MEMORY_SCOPE_AGENT);
      __hip_atomic_store(&b->phase, ph + 1u, __ATOMIC_RELEASE, __HIP_MEMORY_SCOPE_AGENT);
    } else {
      // RELAXED spin: no per-iteration cache invalidate
      while (__hip_atomic_load(&b->phase, __ATOMIC_RELAXED, __HIP_MEMORY_SCOPE_AGENT) == ph)
        __builtin_amdgcn_s_sleep(4);
    }
    __threadfence();   // acquire: invalidate stale L1/L2 once
  }
  __syncthreads();
}

struct KParams {
  const float *x, *w_enc, *w1, *wd, *w2, *w_dec;
  const float *g1, *bb1, *m1, *v1;
  const float *g2, *bb2, *m2, *v2;
  const float *g3, *bb3, *m3, *v3;
  float *out;
  float *xe, *h, *y;
  float *s1, *o1, *s2, *o2, *s3, *o3;
  unsigned short *zb;          // z in bf16
  short *w1b, *w2b;
  Bar *bars;                   // [0]=global, [1+n]=per-batch-n (52 blocks)
};

__global__ __launch_bounds__(NTHR) void tasnet_persistent(KParams p) {
  const int tid = threadIdx.x;
  const int bid = blockIdx.x;
  const int gtid = bid * NTHR + tid;

  const int g = bid >> 2, y4 = bid & 3;
  const int xt = g % 13, n = g / 13;
  const int l0 = xt * 64;

  Bar* gbar = p.bars;
  Bar* nbar = p.bars + 1 + n;

  // B tile, aliased: stage1 [64][264] shorts, stage2 [64][520] shorts (66.5 KB)
  __shared__ __align__(16) short BsBuf[64 * 520];

  // ---------------- phase 0: BN fold + weight cvt + encoder ----------------
  for (int i = gtid; i < NB_ * C_; i += NTH_G) {
    float s = p.g1[i] * rsqrtf(p.v1[i] + EPS_);
    p.s1[i] = s; p.o1[i] = p.bb1[i] - p.m1[i] * s;
  }
  for (int i = gtid; i < NB_ * D_; i += NTH_G) {
    float s2 = p.g2[i] * rsqrtf(p.v2[i] + EPS_);
    p.s2[i] = s2; p.o2[i] = p.bb2[i] - p.m2[i] * s2;
    float s3 = p.g3[i] * rsqrtf(p.v3[i] + EPS_);
    p.s3[i] = s3; p.o3[i] = p.bb3[i] - p.m3[i] * s3;
  }
  for (int i = gtid; i < NB_ * D_ * C_ / 4; i += NTH_G) {
    float4 a = ((const float4*)p.w1)[i];
    float4 b = ((const float4*)p.w2)[i];
    shortx4 sa, sb;
    sa[0] = f2bf(a.x); sa[1] = f2bf(a.y); sa[2] = f2bf(a.z); sa[3] = f2bf(a.w);
    sb[0] = f2bf(b.x); sb[1] = f2bf(b.y); sb[2] = f2bf(b.z); sb[3] = f2bf(b.w);
    *(shortx4*)&p.w1b[4 * i] = sa;
    *(shortx4*)&p.w2b[4 * i] = sb;
  }
  for (int idx = gtid; idx < NBATCH * C_ * L_; idx += NTH_G) {
    int l = idx % L_;
    int c = (idx / L_) % C_;
    int nn = idx / (L_ * C_);
    const float* xn = p.x + (size_t)nn * T_;
    const float* w = p.w_enc + c * FK_;
    int t0 = l * 10 - 20;
    float acc = 0.f;
#pragma unroll
    for (int k = 0; k < FK_; k++) {
      int t = t0 + k;
      float xv = (t >= 0 && t < T_) ? xn[t] : 0.f;
      acc = fmaf(xv, w[k], acc);
    }
    p.xe[idx] = acc;
    p.h[idx] = acc;
  }
  bar_sync(gbar, NBLK, tid);

  // thread roles
  const int col = tid & 63, kslice = tid >> 6;
  const int lB = l0 + col;
  const bool lv = lB < L_;
  const int wv = tid >> 6, lane = tid & 63;
  const int wr = wv >> 1, wc = wv & 1;
  const int frow = lane & 15, kg = lane >> 4;
  const float* hn = p.h + (size_t)n * (C_ * L_);
  float* hw = p.h + (size_t)n * (C_ * L_);
  const unsigned short* zbr = p.zb + (size_t)n * (D_ * L_);
  unsigned short* zbw = p.zb + (size_t)n * (D_ * L_);

  // ---------------- 32 residual blocks ----------------
  for (int layer = 0; layer < NB_; ++layer) {
    const int dil = 1 << (layer & 7);

    // ===== stage1: z = BN2( W1 @ BN1(h) ); tile d:[y4*128,+128) x l:[l0,+64)
    {
      const short* W1 = p.w1b + (size_t)layer * D_ * C_;
      const float* s1p = p.s1 + layer * C_;
      const float* o1p = p.o1 + layer * C_;
      const int d0 = y4 * 128;
      // B staging: full K=256 (BN params are wave-uniform -> scalar loads)
#pragma unroll
      for (int it = 0; it < 4; ++it) {
        int k = it * 64 + kslice * 8;
        bf16x8 pb;
#pragma unroll
        for (int q = 0; q < 8; ++q) {
          float v = lv ? hn[(size_t)(k + q) * L_ + lB] : 0.f;
          pb[q] = f2bf(fmaf(v, s1p[k + q], o1p[k + q]));
        }
        *(bf16x8*)&BsBuf[col * 264 + k] = pb;
      }
      __syncthreads();
      // MFMA: wave tile 32(d) x 32(l)
      f32x4 acc[2][2] = {};
      const short* Wb = W1 + (size_t)(d0 + wr * 32 + frow) * C_;
#pragma unroll
      for (int k0 = 0; k0 < 8; ++k0) {
        int kb = k0 * 32 + kg * 8;
        bf16x8 b0 = *(bf16x8*)&BsBuf[(wc * 32 + frow) * 264 + kb];
        bf16x8 b1 = *(bf16x8*)&BsBuf[(wc * 32 + 16 + frow) * 264 + kb];
#pragma unroll
        for (int ia = 0; ia < 2; ++ia) {
          bf16x8 af = *(const bf16x8*)(Wb + (size_t)ia * 16 * C_ + kb);
          acc[ia][0] = __builtin_amdgcn_mfma_f32_16x16x32_bf16(af, b0, acc[ia][0], 0, 0, 0);
          acc[ia][1] = __builtin_amdgcn_mfma_f32_16x16x32_bf16(af, b1, acc[ia][1], 0, 0, 0);
        }
      }
      // epilogue: z(bf16) = acc*s2 + o2
      const float* s2p = p.s2 + layer * D_;
      const float* o2p = p.o2 + layer * D_;
#pragma unroll
      for (int ia = 0; ia < 2; ++ia) {
        int dbase = d0 + wr * 32 + ia * 16 + kg * 4;
#pragma unroll
        for (int jj = 0; jj < 4; ++jj) {
          int d = dbase + jj;
          float sc = s2p[d], bi = o2p[d];
#pragma unroll
          for (int jb = 0; jb < 2; ++jb) {
            int l = l0 + wc * 32 + jb * 16 + frow;
            if (l < L_)
              zbw[(size_t)d * L_ + l] = (unsigned short)f2bf(fmaf(acc[ia][jb][jj], sc, bi));
          }
        }
      }
    }
    bar_sync(nbar, 52, tid);

    // ===== stage2: h += W2 @ BN3(dconv(z)); tile c:[y4*64,+64) x l:[l0,+64)
    {
      const short* W2 = p.w2b + (size_t)layer * C_ * D_;
      const float* wdp = p.wd + (size_t)layer * D_ * 3;
      const float* s3p = p.s3 + layer * D_;
      const float* o3p = p.o3 + layer * D_;
      const int c0 = y4 * 64;
      const bool lvm = lv && (lB >= dil);
      const bool lvp = lv && (lB + dil < L_);
      // B staging: full K=512, dconv+BN3 fused (params wave-uniform)
#pragma unroll
      for (int it = 0; it < 8; ++it) {
        int krel = it * 64 + kslice * 8;
        bf16x8 pb;
#pragma unroll
        for (int q = 0; q < 8; ++q) {
          int d = krel + q;
          const unsigned short* zd = zbr + (size_t)d * L_;
          float m = lv ? bf2f(zd[lB]) * wdp[3 * d + 1] : 0.f;
          if (lvm) m = fmaf(bf2f(zd[lB - dil]), wdp[3 * d], m);
          if (lvp) m = fmaf(bf2f(zd[lB + dil]), wdp[3 * d + 2], m);
          pb[q] = f2bf(fmaf(m, s3p[d], o3p[d]));
        }
        *(bf16x8*)&BsBuf[col * 520 + krel] = pb;
      }
      __syncthreads();
      // MFMA: wave tile 16(c) x 32(l), K=512
      f32x4 a2[2] = {};
      const short* Wb2 = W2 + (size_t)(c0 + wr * 16 + frow) * D_;
#pragma unroll
      for (int k0 = 0; k0 < 16; ++k0) {
        int kb = k0 * 32 + kg * 8;
        bf16x8 b0 = *(bf16x8*)&BsBuf[(wc * 32 + frow) * 520 + kb];
        bf16x8 b1 = *(bf16x8*)&BsBuf[(wc * 32 + 16 + frow) * 520 + kb];
        bf16x8 af = *(const bf16x8*)(Wb2 + kb);
        a2[0] = __builtin_amdgcn_mfma_f32_16x16x32_bf16(af, b0, a2[0], 0, 0, 0);
        a2[1] = __builtin_amdgcn_mfma_f32_16x16x32_bf16(af, b1, a2[1], 0, 0, 0);
      }
      // epilogue: h +=
      int cbase = c0 + wr * 16 + kg * 4;
#pragma unroll
      for (int jj = 0; jj < 4; ++jj) {
        int c = cbase + jj;
#pragma unroll
        for (int jb = 0; jb < 2; ++jb) {
          int l = l0 + wc * 32 + jb * 16 + frow;
          if (l < L_) hw[(size_t)c * L_ + l] += a2[jb][jj];
        }
      }
    }
    bar_sync(nbar, 52, tid);
  }

  bar_sync(gbar, NBLK, tid);

  // ---------------- mask: y = xe * sigmoid(h) ----------------
  for (int idx = gtid; idx < NBATCH * C_ * L_; idx += NTH_G) {
    float hv = p.h[idx];
    p.y[idx] = p.xe[idx] / (1.f + expf(-hv));
  }
  bar_sync(gbar, NBLK, tid);

  // ---------------- decoder ----------------
  for (int idx = gtid; idx < NBATCH * T_; idx += NTH_G) {
    int t = idx % T_;
    int nn = idx / T_;
    int tt = t + FK_;
    int lq = tt / 10;      // in [2, 801]
    int k0 = tt % 10;
    const float* yn = p.y + (size_t)nn * C_ * L_;
    float acc = 0.f;
#pragma unroll 8
    for (int c = 0; c < C_; c++) {
      const float* yr = yn + (size_t)c * L_;
      const float* wr2 = p.w_dec + c * FK_;
      acc = fmaf(yr[lq], wr2[k0], acc);
      acc = fmaf(yr[lq - 1], wr2[k0 + 10], acc);
    }
    p.out[idx] = acc;
  }
}

extern "C" void kernel_launch(void* const* d_in, const int* in_sizes, int n_in,
                              void* d_out, int out_size, void* d_ws, size_t ws_size,
                              hipStream_t stream) {
  const size_t NCL = (size_t)NBATCH * C_ * L_;      // 822272
  const size_t NDL = (size_t)NBATCH * D_ * L_;      // 1644544

  KParams hp;
  hp.x     = (const float*)d_in[0];
  hp.w_enc = (const float*)d_in[1];
  hp.w1    = (const float*)d_in[2];
  hp.wd    = (const float*)d_in[3];
  hp.w2    = (const float*)d_in[4];
  hp.w_dec = (const float*)d_in[5];
  hp.g1 = (const float*)d_in[6];  hp.bb1 = (const float*)d_in[7];
  hp.m1 = (const float*)d_in[8];  hp.v1  = (const float*)d_in[9];
  hp.g2 = (const float*)d_in[10]; hp.bb2 = (const float*)d_in[11];
  hp.m2 = (const float*)d_in[12]; hp.v2  = (const float*)d_in[13];
  hp.g3 = (const float*)d_in[14]; hp.bb3 = (const float*)d_in[15];
  hp.m3 = (const float*)d_in[16]; hp.v3  = (const float*)d_in[17];
  hp.out = (float*)d_out;

  char* cur = (char*)d_ws;
  auto take = [&](size_t bytes) { char* r = cur; cur += (bytes + 255) & ~(size_t)255; return r; };
  hp.bars = (Bar*)take(8 * sizeof(Bar));
  hp.xe = (float*)take(NCL * 4);
  hp.h  = (float*)take(NCL * 4);
  hp.y  = (float*)take(NCL * 4);
  hp.s1 = (float*)take(NB_ * C_ * 4);
  hp.o1 = (float*)take(NB_ * C_ * 4);
  hp.s2 = (float*)take(NB_ * D_ * 4);
  hp.o2 = (float*)take(NB_ * D_ * 4);
  hp.s3 = (float*)take(NB_ * D_ * 4);
  hp.o3 = (float*)take(NB_ * D_ * 4);
  hp.zb  = (unsigned short*)take(NDL * 2);
  hp.w1b = (short*)take((size_t)NB_ * D_ * C_ * 2);
  hp.w2b = (short*)take((size_t)NB_ * D_ * C_ * 2);

  hipMemsetAsync(d_ws, 0, 8 * sizeof(Bar), stream);
  tasnet_persistent<<<dim3(NBLK), dim3(NTHR), 0, stream>>>(hp);
}

// Round 8
// 3857.402 us; speedup vs baseline: 1.7951x; 1.1237x over previous
//
#include <hip/hip_runtime.h>
#include <cstddef>

#define T_     8000
#define L_     803
#define C_     256
#define D_     512
#define NB_    32
#define FK_    20
#define NBATCH 4
#define EPS_   1e-5f

#define NBLK   208        // 52 groups (13 l-tiles x 4 batch) x 4 y-slices
#define NTHR   512        // 8 waves
#define NTH_G  (NBLK * NTHR)

typedef __attribute__((ext_vector_type(8))) short bf16x8;
typedef __attribute__((ext_vector_type(4))) short shortx4;
typedef __attribute__((ext_vector_type(4))) float f32x4;

__device__ __forceinline__ short f2bf(float x) {
  unsigned u = __float_as_uint(x);
  u += 0x7FFF + ((u >> 16) & 1);   // RNE
  return (short)(u >> 16);
}
__device__ __forceinline__ float bf2f(unsigned short u) {
  return __uint_as_float(((unsigned)u) << 16);
}

// ---- agent-coherent (sc1, L2-bypass -> Infinity Cache) accessors ----
__device__ __forceinline__ float cohL(const float* p) {
  return __hip_atomic_load((float*)p, __ATOMIC_RELAXED, __HIP_MEMORY_SCOPE_AGENT);
}
__device__ __forceinline__ void cohS(float* p, float v) {
  __hip_atomic_store(p, v, __ATOMIC_RELAXED, __HIP_MEMORY_SCOPE_AGENT);
}
__device__ __forceinline__ unsigned short cohLu(const unsigned short* p) {
  return __hip_atomic_load((unsigned short*)p, __ATOMIC_RELAXED, __HIP_MEMORY_SCOPE_AGENT);
}
__device__ __forceinline__ void cohSu(unsigned short* p, unsigned short v) {
  __hip_atomic_store(p, v, __ATOMIC_RELAXED, __HIP_MEMORY_SCOPE_AGENT);
}

// ---- barriers ----
struct __align__(64) Bar { unsigned cnt; unsigned phase; unsigned pad[14]; };

// light: NO cache maintenance. Correct because all cross-block data uses
// sc1 (L3-coherent) accesses and __syncthreads drains vmcnt beforehand.
__device__ __forceinline__ void bar_light(Bar* b, unsigned nblk, int tid) {
  __syncthreads();   // all waves' stores retired (vmcnt drained at s_barrier)
  if (tid == 0) {
    unsigned ph = __hip_atomic_load(&b->phase, __ATOMIC_RELAXED, __HIP_MEMORY_SCOPE_AGENT);
    unsigned prev = __hip_atomic_fetch_add(&b->cnt, 1u, __ATOMIC_RELAXED, __HIP_MEMORY_SCOPE_AGENT);
    if (prev == nblk - 1) {
      __hip_atomic_store(&b->cnt, 0u, __ATOMIC_RELAXED, __HIP_MEMORY_SCOPE_AGENT);
      __hip_atomic_store(&b->phase, ph + 1u, __ATOMIC_RELAXED, __HIP_MEMORY_SCOPE_AGENT);
    } else {
      while (__hip_atomic_load(&b->phase, __ATOMIC_RELAXED, __HIP_MEMORY_SCOPE_AGENT) == ph)
        __builtin_amdgcn_s_sleep(4);
    }
  }
  __syncthreads();
}

// heavy: full fences (phase boundaries only; makes normal-cached writes visible)
__device__ __forceinline__ void bar_heavy(Bar* b, unsigned nblk, int tid) {
  __syncthreads();
  if (tid == 0) {
    __threadfence();
    unsigned ph = __hip_atomic_load(&b->phase, __ATOMIC_RELAXED, __HIP_MEMORY_SCOPE_AGENT);
    unsigned prev = __hip_atomic_fetch_add(&b->cnt, 1u, __ATOMIC_RELAXED, __HIP_MEMORY_SCOPE_AGENT);
    if (prev == nblk - 1) {
      __hip_atomic_store(&b->cnt, 0u, __ATOMIC_RELAXED, __HIP_MEMORY_SCOPE_AGENT);
      __hip_atomic_store(&b->phase, ph + 1u, __ATOMIC_RELEASE, __HIP_MEMORY_SCOPE_AGENT);
    } else {
      while (__hip_atomic_load(&b->phase, __ATOMIC_RELAXED, __HIP_MEMORY_SCOPE_AGENT) == ph)
        __builtin_amdgcn_s_sleep(4);
    }
    __threadfence();
  }
  __syncthreads();
}

struct KParams {
  const float *x, *w_enc, *w1, *wd, *w2, *w_dec;
  const float *g1, *bb1, *m1, *v1;
  const float *g2, *bb2, *m2, *v2;
  const float *g3, *bb3, *m3, *v3;
  float *out;
  float *xe, *h, *y;
  float *s1, *o1, *s2, *o2, *s3, *o3;
  unsigned short *zb;          // z in bf16 (sc1-accessed)
  short *w1b, *w2b;
  Bar *bars;                   // [0]=global, [1+n]=per-batch-n (52 blocks)
};

__global__ __launch_bounds__(NTHR) void tasnet_persistent(KParams p) {
  const int tid = threadIdx.x;
  const int bid = blockIdx.x;
  const int gtid = bid * NTHR + tid;

  const int g = bid >> 2, y4 = bid & 3;
  const int xt = g % 13, n = g / 13;
  const int l0 = xt * 64;

  Bar* gbar = p.bars;
  Bar* nbar = p.bars + 1 + n;

  __shared__ __align__(16) short BsBuf[64 * 520];   // 66.5 KB

  // ---------------- phase 0: BN fold + weight cvt + encoder ----------------
  for (int i = gtid; i < NB_ * C_; i += NTH_G) {
    float s = p.g1[i] * rsqrtf(p.v1[i] + EPS_);
    p.s1[i] = s; p.o1[i] = p.bb1[i] - p.m1[i] * s;
  }
  for (int i = gtid; i < NB_ * D_; i += NTH_G) {
    float s2 = p.g2[i] * rsqrtf(p.v2[i] + EPS_);
    p.s2[i] = s2; p.o2[i] = p.bb2[i] - p.m2[i] * s2;
    float s3 = p.g3[i] * rsqrtf(p.v3[i] + EPS_);
    p.s3[i] = s3; p.o3[i] = p.bb3[i] - p.m3[i] * s3;
  }
  for (int i = gtid; i < NB_ * D_ * C_ / 4; i += NTH_G) {
    float4 a = ((const float4*)p.w1)[i];
    float4 b = ((const float4*)p.w2)[i];
    shortx4 sa, sb;
    sa[0] = f2bf(a.x); sa[1] = f2bf(a.y); sa[2] = f2bf(a.z); sa[3] = f2bf(a.w);
    sb[0] = f2bf(b.x); sb[1] = f2bf(b.y); sb[2] = f2bf(b.z); sb[3] = f2bf(b.w);
    *(shortx4*)&p.w1b[4 * i] = sa;
    *(shortx4*)&p.w2b[4 * i] = sb;
  }
  for (int idx = gtid; idx < NBATCH * C_ * L_; idx += NTH_G) {
    int l = idx % L_;
    int c = (idx / L_) % C_;
    int nn = idx / (L_ * C_);
    const float* xn = p.x + (size_t)nn * T_;
    const float* w = p.w_enc + c * FK_;
    int t0 = l * 10 - 20;
    float acc = 0.f;
#pragma unroll
    for (int k = 0; k < FK_; k++) {
      int t = t0 + k;
      float xv = (t >= 0 && t < T_) ? xn[t] : 0.f;
      acc = fmaf(xv, w[k], acc);
    }
    p.xe[idx] = acc;
    p.h[idx] = acc;   // normal store; heavy barrier below publishes it
  }
  bar_heavy(gbar, NBLK, tid);

  // thread roles
  const int col = tid & 63, kslice = tid >> 6;
  const int lB = l0 + col;
  const bool lv = lB < L_;
  const int wv = tid >> 6, lane = tid & 63;
  const int wr = wv >> 1, wc = wv & 1;
  const int frow = lane & 15, kg = lane >> 4;
  float* hn = p.h + (size_t)n * (C_ * L_);
  unsigned short* zn = p.zb + (size_t)n * (D_ * L_);

  // ---------------- 32 residual blocks ----------------
  for (int layer = 0; layer < NB_; ++layer) {
    const int dil = 1 << (layer & 7);

    // ===== stage1: z = BN2( W1 @ BN1(h) ); tile d:[y4*128,+128) x l:[l0,+64)
    {
      const short* W1 = p.w1b + (size_t)layer * D_ * C_;
      const float* s1p = p.s1 + layer * C_;
      const float* o1p = p.o1 + layer * C_;
      const int d0 = y4 * 128;
#pragma unroll
      for (int it = 0; it < 4; ++it) {
        int k = it * 64 + kslice * 8;
        bf16x8 pb;
#pragma unroll
        for (int q = 0; q < 8; ++q) {
          float v = lv ? cohL(&hn[(size_t)(k + q) * L_ + lB]) : 0.f;
          pb[q] = f2bf(fmaf(v, s1p[k + q], o1p[k + q]));
        }
        *(bf16x8*)&BsBuf[col * 264 + k] = pb;
      }
      __syncthreads();
      f32x4 acc[2][2] = {};
      const short* Wb = W1 + (size_t)(d0 + wr * 32 + frow) * C_;
#pragma unroll
      for (int k0 = 0; k0 < 8; ++k0) {
        int kb = k0 * 32 + kg * 8;
        bf16x8 b0 = *(bf16x8*)&BsBuf[(wc * 32 + frow) * 264 + kb];
        bf16x8 b1 = *(bf16x8*)&BsBuf[(wc * 32 + 16 + frow) * 264 + kb];
#pragma unroll
        for (int ia = 0; ia < 2; ++ia) {
          bf16x8 af = *(const bf16x8*)(Wb + (size_t)ia * 16 * C_ + kb);
          acc[ia][0] = __builtin_amdgcn_mfma_f32_16x16x32_bf16(af, b0, acc[ia][0], 0, 0, 0);
          acc[ia][1] = __builtin_amdgcn_mfma_f32_16x16x32_bf16(af, b1, acc[ia][1], 0, 0, 0);
        }
      }
      const float* s2p = p.s2 + layer * D_;
      const float* o2p = p.o2 + layer * D_;
#pragma unroll
      for (int ia = 0; ia < 2; ++ia) {
        int dbase = d0 + wr * 32 + ia * 16 + kg * 4;
#pragma unroll
        for (int jj = 0; jj < 4; ++jj) {
          int d = dbase + jj;
          float sc = s2p[d], bi = o2p[d];
#pragma unroll
          for (int jb = 0; jb < 2; ++jb) {
            int l = l0 + wc * 32 + jb * 16 + frow;
            if (l < L_)
              cohSu(&zn[(size_t)d * L_ + l],
                    (unsigned short)f2bf(fmaf(acc[ia][jb][jj], sc, bi)));
          }
        }
      }
    }
    bar_light(nbar, 52, tid);

    // ===== stage2: h += W2 @ BN3(dconv(z)); tile c:[y4*64,+64) x l:[l0,+64)
    {
      const short* W2 = p.w2b + (size_t)layer * C_ * D_;
      const float* wdp = p.wd + (size_t)layer * D_ * 3;
      const float* s3p = p.s3 + layer * D_;
      const float* o3p = p.o3 + layer * D_;
      const int c0 = y4 * 64;
      const bool lvm = lv && (lB >= dil);
      const bool lvp = lv && (lB + dil < L_);
#pragma unroll
      for (int it = 0; it < 8; ++it) {
        int krel = it * 64 + kslice * 8;
        bf16x8 pb;
#pragma unroll
        for (int q = 0; q < 8; ++q) {
          int d = krel + q;
          const unsigned short* zd = zn + (size_t)d * L_;
          float m = lv ? bf2f(cohLu(&zd[lB])) * wdp[3 * d + 1] : 0.f;
          if (lvm) m = fmaf(bf2f(cohLu(&zd[lB - dil])), wdp[3 * d], m);
          if (lvp) m = fmaf(bf2f(cohLu(&zd[lB + dil])), wdp[3 * d + 2], m);
          pb[q] = f2bf(fmaf(m, s3p[d], o3p[d]));
        }
        *(bf16x8*)&BsBuf[col * 520 + krel] = pb;
      }
      __syncthreads();
      f32x4 a2[2] = {};
      const short* Wb2 = W2 + (size_t)(c0 + wr * 16 + frow) * D_;
#pragma unroll
      for (int k0 = 0; k0 < 16; ++k0) {
        int kb = k0 * 32 + kg * 8;
        bf16x8 b0 = *(bf16x8*)&BsBuf[(wc * 32 + frow) * 520 + kb];
        bf16x8 b1 = *(bf16x8*)&BsBuf[(wc * 32 + 16 + frow) * 520 + kb];
        bf16x8 af = *(const bf16x8*)(Wb2 + kb);
        a2[0] = __builtin_amdgcn_mfma_f32_16x16x32_bf16(af, b0, a2[0], 0, 0, 0);
        a2[1] = __builtin_amdgcn_mfma_f32_16x16x32_bf16(af, b1, a2[1], 0, 0, 0);
      }
      int cbase = c0 + wr * 16 + kg * 4;
#pragma unroll
      for (int jj = 0; jj < 4; ++jj) {
        int c = cbase + jj;
#pragma unroll
        for (int jb = 0; jb < 2; ++jb) {
          int l = l0 + wc * 32 + jb * 16 + frow;
          if (l < L_) {
            float* hp_ = &hn[(size_t)c * L_ + l];
            cohS(hp_, cohL(hp_) + a2[jb][jj]);
          }
        }
      }
    }
    bar_light(nbar, 52, tid);
  }

  bar_heavy(gbar, NBLK, tid);   // invalidate stale L2 copies of h before normal reads

  // ---------------- mask: y = xe * sigmoid(h) ----------------
  for (int idx = gtid; idx < NBATCH * C_ * L_; idx += NTH_G) {
    float hv = p.h[idx];
    p.y[idx] = p.xe[idx] / (1.f + expf(-hv));
  }
  bar_heavy(gbar, NBLK, tid);

  // ---------------- decoder ----------------
  for (int idx = gtid; idx < NBATCH * T_; idx += NTH_G) {
    int t = idx % T_;
    int nn = idx / T_;
    int tt = t + FK_;
    int lq = tt / 10;      // in [2, 801]
    int k0 = tt % 10;
    const float* yn = p.y + (size_t)nn * C_ * L_;
    float acc = 0.f;
#pragma unroll 8
    for (int c = 0; c < C_; c++) {
      const float* yr = yn + (size_t)c * L_;
      const float* wr2 = p.w_dec + c * FK_;
      acc = fmaf(yr[lq], wr2[k0], acc);
      acc = fmaf(yr[lq - 1], wr2[k0 + 10], acc);
    }
    p.out[idx] = acc;
  }
}

extern "C" void kernel_launch(void* const* d_in, const int* in_sizes, int n_in,
                              void* d_out, int out_size, void* d_ws, size_t ws_size,
                              hipStream_t stream) {
  const size_t NCL = (size_t)NBATCH * C_ * L_;      // 822272
  const size_t NDL = (size_t)NBATCH * D_ * L_;      // 1644544

  KParams hp;
  hp.x     = (const float*)d_in[0];
  hp.w_enc = (const float*)d_in[1];
  hp.w1    = (const float*)d_in[2];
  hp.wd    = (const float*)d_in[3];
  hp.w2    = (const float*)d_in[4];
  hp.w_dec = (const float*)d_in[5];
  hp.g1 = (const float*)d_in[6];  hp.bb1 = (const float*)d_in[7];
  hp.m1 = (const float*)d_in[8];  hp.v1  = (const float*)d_in[9];
  hp.g2 = (const float*)d_in[10]; hp.bb2 = (const float*)d_in[11];
  hp.m2 = (const float*)d_in[12]; hp.v2  = (const float*)d_in[13];
  hp.g3 = (const float*)d_in[14]; hp.bb3 = (const float*)d_in[15];
  hp.m3 = (const float*)d_in[16]; hp.v3  = (const float*)d_in[17];
  hp.out = (float*)d_out;

  char* cur = (char*)d_ws;
  auto take = [&](size_t bytes) { char* r = cur; cur += (bytes + 255) & ~(size_t)255; return r; };
  hp.bars = (Bar*)take(8 * sizeof(Bar));
  hp.xe = (float*)take(NCL * 4);
  hp.h  = (float*)take(NCL * 4);
  hp.y  = (float*)take(NCL * 4);
  hp.s1 = (float*)take(NB_ * C_ * 4);
  hp.o1 = (float*)take(NB_ * C_ * 4);
  hp.s2 = (float*)take(NB_ * D_ * 4);
  hp.o2 = (float*)take(NB_ * D_ * 4);
  hp.s3 = (float*)take(NB_ * D_ * 4);
  hp.o3 = (float*)take(NB_ * D_ * 4);
  hp.zb  = (unsigned short*)take(NDL * 2);
  hp.w1b = (short*)take((size_t)NB_ * D_ * C_ * 2);
  hp.w2b = (short*)take((size_t)NB_ * D_ * C_ * 2);

  hipMemsetAsync(d_ws, 0, 8 * sizeof(Bar), stream);
  tasnet_persistent<<<dim3(NBLK), dim3(NTHR), 0, stream>>>(hp);
}

// Round 9
// 2994.047 us; speedup vs baseline: 2.3127x; 1.2884x over previous
//
#include <hip/hip_runtime.h>
#include <cstddef>

#define T_     8000
#define L_     803
#define C_     256
#define D_     512
#define NB_    32
#define FK_    20
#define NBATCH 4
#define EPS_   1e-5f

#define NBLK   208        // 52 groups (13 l-tiles x 4 batch) x 4 y-slices
#define NTHR   512        // 8 waves
#define NTH_G  (NBLK * NTHR)

typedef __attribute__((ext_vector_type(8))) short bf16x8;
typedef __attribute__((ext_vector_type(4))) short shortx4;
typedef __attribute__((ext_vector_type(4))) float f32x4;

__device__ __forceinline__ short f2bf(float x) {
  unsigned u = __float_as_uint(x);
  u += 0x7FFF + ((u >> 16) & 1);   // RNE
  return (short)(u >> 16);
}
__device__ __forceinline__ float bf2f(unsigned short u) {
  return __uint_as_float(((unsigned)u) << 16);
}

// sc1 STORES only: write-through to IF$ (coherent point), bypass own L2.
// Reads are NORMAL cached loads — correct because every communicated address
// is written exactly once per call (buffer rotation) and dispatch boundaries
// are HSA acquire/release (no stale lines from prior dispatches).
__device__ __forceinline__ void cohS(float* p, float v) {
  __hip_atomic_store(p, v, __ATOMIC_RELAXED, __HIP_MEMORY_SCOPE_AGENT);
}
__device__ __forceinline__ void cohSu(unsigned short* p, unsigned short v) {
  __hip_atomic_store(p, v, __ATOMIC_RELAXED, __HIP_MEMORY_SCOPE_AGENT);
}

// ---- barriers ----
struct __align__(64) Bar { unsigned cnt; unsigned phase; unsigned pad[14]; };

// light: no cache maintenance (see protocol above)
__device__ __forceinline__ void bar_light(Bar* b, unsigned nblk, int tid) {
  __syncthreads();   // drains vmcnt: sc1 stores at IF$ before ticket
  if (tid == 0) {
    unsigned ph = __hip_atomic_load(&b->phase, __ATOMIC_RELAXED, __HIP_MEMORY_SCOPE_AGENT);
    unsigned prev = __hip_atomic_fetch_add(&b->cnt, 1u, __ATOMIC_RELAXED, __HIP_MEMORY_SCOPE_AGENT);
    if (prev == nblk - 1) {
      __hip_atomic_store(&b->cnt, 0u, __ATOMIC_RELAXED, __HIP_MEMORY_SCOPE_AGENT);
      __hip_atomic_store(&b->phase, ph + 1u, __ATOMIC_RELAXED, __HIP_MEMORY_SCOPE_AGENT);
    } else {
      while (__hip_atomic_load(&b->phase, __ATOMIC_RELAXED, __HIP_MEMORY_SCOPE_AGENT) == ph)
        __builtin_amdgcn_s_sleep(4);
    }
  }
  __syncthreads();
}

// heavy: full fences — publishes normal cached stores (phase boundaries only)
__device__ __forceinline__ void bar_heavy(Bar* b, unsigned nblk, int tid) {
  __syncthreads();
  if (tid == 0) {
    __threadfence();
    unsigned ph = __hip_atomic_load(&b->phase, __ATOMIC_RELAXED, __HIP_MEMORY_SCOPE_AGENT);
    unsigned prev = __hip_atomic_fetch_add(&b->cnt, 1u, __ATOMIC_RELAXED, __HIP_MEMORY_SCOPE_AGENT);
    if (prev == nblk - 1) {
      __hip_atomic_store(&b->cnt, 0u, __ATOMIC_RELAXED, __HIP_MEMORY_SCOPE_AGENT);
      __hip_atomic_store(&b->phase, ph + 1u, __ATOMIC_RELEASE, __HIP_MEMORY_SCOPE_AGENT);
    } else {
      while (__hip_atomic_load(&b->phase, __ATOMIC_RELAXED, __HIP_MEMORY_SCOPE_AGENT) == ph)
        __builtin_amdgcn_s_sleep(4);
    }
    __threadfence();
  }
  __syncthreads();
}

struct KParams {
  const float *x, *w_enc, *w1, *wd, *w2, *w_dec;
  const float *g1, *bb1, *m1, *v1;
  const float *g2, *bb2, *m2, *v2;
  const float *g3, *bb3, *m3, *v3;
  float *out;
  float *xe, *y;
  float *hb;                   // 33 rotating h buffers [buf][n][c][l]
  unsigned short *zb;          // 32 rotating z buffers (bf16) [buf][n][d][l]
  float *s1, *o1, *s2, *o2, *s3, *o3;
  short *w1b, *w2b;
  Bar *bars;                   // [0]=global, [1+n]=per-batch-n (52 blocks)
};

__global__ __launch_bounds__(NTHR) void tasnet_persistent(KParams p) {
  const int tid = threadIdx.x;
  const int bid = blockIdx.x;
  const int gtid = bid * NTHR + tid;

  const int g = bid >> 2, y4 = bid & 3;
  const int xt = g % 13, n = g / 13;
  const int l0 = xt * 64;

  Bar* gbar = p.bars;
  Bar* nbar = p.bars + 1 + n;

  const size_t NCL = (size_t)NBATCH * C_ * L_;
  const size_t NDL = (size_t)NBATCH * D_ * L_;

  __shared__ __align__(16) short BsBuf[64 * 520];   // 66.5 KB

  // ---------------- phase 0: BN fold + weight cvt + encoder ----------------
  for (int i = gtid; i < NB_ * C_; i += NTH_G) {
    float s = p.g1[i] * rsqrtf(p.v1[i] + EPS_);
    p.s1[i] = s; p.o1[i] = p.bb1[i] - p.m1[i] * s;
  }
  for (int i = gtid; i < NB_ * D_; i += NTH_G) {
    float s2 = p.g2[i] * rsqrtf(p.v2[i] + EPS_);
    p.s2[i] = s2; p.o2[i] = p.bb2[i] - p.m2[i] * s2;
    float s3 = p.g3[i] * rsqrtf(p.v3[i] + EPS_);
    p.s3[i] = s3; p.o3[i] = p.bb3[i] - p.m3[i] * s3;
  }
  for (int i = gtid; i < NB_ * D_ * C_ / 4; i += NTH_G) {
    float4 a = ((const float4*)p.w1)[i];
    float4 b = ((const float4*)p.w2)[i];
    shortx4 sa, sb;
    sa[0] = f2bf(a.x); sa[1] = f2bf(a.y); sa[2] = f2bf(a.z); sa[3] = f2bf(a.w);
    sb[0] = f2bf(b.x); sb[1] = f2bf(b.y); sb[2] = f2bf(b.z); sb[3] = f2bf(b.w);
    *(shortx4*)&p.w1b[4 * i] = sa;
    *(shortx4*)&p.w2b[4 * i] = sb;
  }
  for (int idx = gtid; idx < NBATCH * C_ * L_; idx += NTH_G) {
    int l = idx % L_;
    int c = (idx / L_) % C_;
    int nn = idx / (L_ * C_);
    const float* xn = p.x + (size_t)nn * T_;
    const float* w = p.w_enc + c * FK_;
    int t0 = l * 10 - 20;
    float acc = 0.f;
#pragma unroll
    for (int k = 0; k < FK_; k++) {
      int t = t0 + k;
      float xv = (t >= 0 && t < T_) ? xn[t] : 0.f;
      acc = fmaf(xv, w[k], acc);
    }
    p.xe[idx] = acc;
    p.hb[idx] = acc;           // h buffer 0
  }
  bar_heavy(gbar, NBLK, tid);  // publish phase-0 normal stores

  // thread roles
  const int col = tid & 63, kslice = tid >> 6;
  const int lB = l0 + col;
  const bool lv = lB < L_;
  const int wv = tid >> 6, lane = tid & 63;
  const int wr = wv >> 1, wc = wv & 1;
  const int frow = lane & 15, kg = lane >> 4;

  // ---- register-resident h patch: this block's stage2 output fragment ----
  // element (jb,jj): c = y4*64 + wr*16 + kg*4 + jj ; l = l0 + wc*32 + jb*16 + frow
  const int hc0 = y4 * 64 + wr * 16 + kg * 4;
  float hreg[8];
#pragma unroll
  for (int jb = 0; jb < 2; ++jb) {
    int l = l0 + wc * 32 + jb * 16 + frow;
#pragma unroll
    for (int jj = 0; jj < 4; ++jj)
      hreg[jb * 4 + jj] = (l < L_)
        ? p.hb[(size_t)n * (C_ * L_) + (size_t)(hc0 + jj) * L_ + l] : 0.f;
  }

  // ---------------- 32 residual blocks ----------------
  for (int layer = 0; layer < NB_; ++layer) {
    const int dil = 1 << (layer & 7);
    const float* hcur = p.hb + (size_t)layer * NCL + (size_t)n * (C_ * L_);
    float* hnext      = p.hb + (size_t)(layer + 1) * NCL + (size_t)n * (C_ * L_);
    unsigned short* zcur = p.zb + (size_t)layer * NDL + (size_t)n * (D_ * L_);

    // ===== stage1: z = BN2( W1 @ BN1(h) ); tile d:[y4*128,+128) x l:[l0,+64)
    {
      const short* W1 = p.w1b + (size_t)layer * D_ * C_;
      const float* s1p = p.s1 + layer * C_;
      const float* o1p = p.o1 + layer * C_;
      const int d0 = y4 * 128;
#pragma unroll
      for (int it = 0; it < 4; ++it) {
        int k = it * 64 + kslice * 8;
        bf16x8 pb;
#pragma unroll
        for (int q = 0; q < 8; ++q) {
          float v = lv ? hcur[(size_t)(k + q) * L_ + lB] : 0.f;   // normal cached
          pb[q] = f2bf(fmaf(v, s1p[k + q], o1p[k + q]));
        }
        *(bf16x8*)&BsBuf[col * 264 + k] = pb;
      }
      __syncthreads();
      f32x4 acc[2][2] = {};
      const short* Wb = W1 + (size_t)(d0 + wr * 32 + frow) * C_;
#pragma unroll
      for (int k0 = 0; k0 < 8; ++k0) {
        int kb = k0 * 32 + kg * 8;
        bf16x8 b0 = *(bf16x8*)&BsBuf[(wc * 32 + frow) * 264 + kb];
        bf16x8 b1 = *(bf16x8*)&BsBuf[(wc * 32 + 16 + frow) * 264 + kb];
#pragma unroll
        for (int ia = 0; ia < 2; ++ia) {
          bf16x8 af = *(const bf16x8*)(Wb + (size_t)ia * 16 * C_ + kb);
          acc[ia][0] = __builtin_amdgcn_mfma_f32_16x16x32_bf16(af, b0, acc[ia][0], 0, 0, 0);
          acc[ia][1] = __builtin_amdgcn_mfma_f32_16x16x32_bf16(af, b1, acc[ia][1], 0, 0, 0);
        }
      }
      const float* s2p = p.s2 + layer * D_;
      const float* o2p = p.o2 + layer * D_;
#pragma unroll
      for (int ia = 0; ia < 2; ++ia) {
        int dbase = y4 * 128 + wr * 32 + ia * 16 + kg * 4;
#pragma unroll
        for (int jj = 0; jj < 4; ++jj) {
          int d = dbase + jj;
          float sc = s2p[d], bi = o2p[d];
#pragma unroll
          for (int jb = 0; jb < 2; ++jb) {
            int l = l0 + wc * 32 + jb * 16 + frow;
            if (l < L_)
              cohSu(&zcur[(size_t)d * L_ + l],
                    (unsigned short)f2bf(fmaf(acc[ia][jb][jj], sc, bi)));
          }
        }
      }
    }
    bar_light(nbar, 52, tid);

    // ===== stage2: h' = h + W2 @ BN3(dconv(z)); tile c:[y4*64,+64) x l:[l0,+64)
    {
      const short* W2 = p.w2b + (size_t)layer * C_ * D_;
      const float* wdp = p.wd + (size_t)layer * D_ * 3;
      const float* s3p = p.s3 + layer * D_;
      const float* o3p = p.o3 + layer * D_;
      const int c0 = y4 * 64;
      const bool lvm = lv && (lB >= dil);
      const bool lvp = lv && (lB + dil < L_);
#pragma unroll
      for (int it = 0; it < 8; ++it) {
        int krel = it * 64 + kslice * 8;
        bf16x8 pb;
#pragma unroll
        for (int q = 0; q < 8; ++q) {
          int d = krel + q;
          const unsigned short* zd = zcur + (size_t)d * L_;     // normal cached
          float m = lv ? bf2f(zd[lB]) * wdp[3 * d + 1] : 0.f;
          if (lvm) m = fmaf(bf2f(zd[lB - dil]), wdp[3 * d], m);
          if (lvp) m = fmaf(bf2f(zd[lB + dil]), wdp[3 * d + 2], m);
          pb[q] = f2bf(fmaf(m, s3p[d], o3p[d]));
        }
        *(bf16x8*)&BsBuf[col * 520 + krel] = pb;
      }
      __syncthreads();
      f32x4 a2[2] = {};
      const short* Wb2 = W2 + (size_t)(c0 + wr * 16 + frow) * D_;
#pragma unroll
      for (int k0 = 0; k0 < 16; ++k0) {
        int kb = k0 * 32 + kg * 8;
        bf16x8 b0 = *(bf16x8*)&BsBuf[(wc * 32 + frow) * 520 + kb];
        bf16x8 b1 = *(bf16x8*)&BsBuf[(wc * 32 + 16 + frow) * 520 + kb];
        bf16x8 af = *(const bf16x8*)(Wb2 + kb);
        a2[0] = __builtin_amdgcn_mfma_f32_16x16x32_bf16(af, b0, a2[0], 0, 0, 0);
        a2[1] = __builtin_amdgcn_mfma_f32_16x16x32_bf16(af, b1, a2[1], 0, 0, 0);
      }
      // epilogue: hreg += r ; publish h' (sc1 store, no load)
#pragma unroll
      for (int jb = 0; jb < 2; ++jb) {
        int l = l0 + wc * 32 + jb * 16 + frow;
#pragma unroll
        for (int jj = 0; jj < 4; ++jj) {
          hreg[jb * 4 + jj] += a2[jb][jj];
          if (l < L_)
            cohS(&hnext[(size_t)(hc0 + jj) * L_ + l], hreg[jb * 4 + jj]);
        }
      }
    }
    bar_light(nbar, 52, tid);
  }

  bar_heavy(gbar, NBLK, tid);

  // ---------------- mask: y = xe * sigmoid(h_final) ----------------
  const float* hfin = p.hb + (size_t)NB_ * NCL;
  for (int idx = gtid; idx < NBATCH * C_ * L_; idx += NTH_G) {
    float hv = hfin[idx];
    p.y[idx] = p.xe[idx] / (1.f + expf(-hv));
  }
  bar_heavy(gbar, NBLK, tid);

  // ---------------- decoder ----------------
  for (int idx = gtid; idx < NBATCH * T_; idx += NTH_G) {
    int t = idx % T_;
    int nn = idx / T_;
    int tt = t + FK_;
    int lq = tt / 10;      // in [2, 801]
    int k0 = tt % 10;
    const float* yn = p.y + (size_t)nn * C_ * L_;
    float acc = 0.f;
#pragma unroll 8
    for (int c = 0; c < C_; c++) {
      const float* yr = yn + (size_t)c * L_;
      const float* wr2 = p.w_dec + c * FK_;
      acc = fmaf(yr[lq], wr2[k0], acc);
      acc = fmaf(yr[lq - 1], wr2[k0 + 10], acc);
    }
    p.out[idx] = acc;
  }
}

extern "C" void kernel_launch(void* const* d_in, const int* in_sizes, int n_in,
                              void* d_out, int out_size, void* d_ws, size_t ws_size,
                              hipStream_t stream) {
  const size_t NCL = (size_t)NBATCH * C_ * L_;      // 822272
  const size_t NDL = (size_t)NBATCH * D_ * L_;      // 1644544

  KParams hp;
  hp.x     = (const float*)d_in[0];
  hp.w_enc = (const float*)d_in[1];
  hp.w1    = (const float*)d_in[2];
  hp.wd    = (const float*)d_in[3];
  hp.w2    = (const float*)d_in[4];
  hp.w_dec = (const float*)d_in[5];
  hp.g1 = (const float*)d_in[6];  hp.bb1 = (const float*)d_in[7];
  hp.m1 = (const float*)d_in[8];  hp.v1  = (const float*)d_in[9];
  hp.g2 = (const float*)d_in[10]; hp.bb2 = (const float*)d_in[11];
  hp.m2 = (const float*)d_in[12]; hp.v2  = (const float*)d_in[13];
  hp.g3 = (const float*)d_in[14]; hp.bb3 = (const float*)d_in[15];
  hp.m3 = (const float*)d_in[16]; hp.v3  = (const float*)d_in[17];
  hp.out = (float*)d_out;

  char* cur = (char*)d_ws;
  auto take = [&](size_t bytes) { char* r = cur; cur += (bytes + 255) & ~(size_t)255; return r; };
  hp.bars = (Bar*)take(8 * sizeof(Bar));
  hp.xe = (float*)take(NCL * 4);
  hp.y  = (float*)take(NCL * 4);
  hp.s1 = (float*)take(NB_ * C_ * 4);
  hp.o1 = (float*)take(NB_ * C_ * 4);
  hp.s2 = (float*)take(NB_ * D_ * 4);
  hp.o2 = (float*)take(NB_ * D_ * 4);
  hp.s3 = (float*)take(NB_ * D_ * 4);
  hp.o3 = (float*)take(NB_ * D_ * 4);
  hp.w1b = (short*)take((size_t)NB_ * D_ * C_ * 2);
  hp.w2b = (short*)take((size_t)NB_ * D_ * C_ * 2);
  hp.hb  = (float*)take((size_t)(NB_ + 1) * NCL * 4);          // 33 bufs
  hp.zb  = (unsigned short*)take((size_t)NB_ * NDL * 2);       // 32 bufs

  hipMemsetAsync(d_ws, 0, 8 * sizeof(Bar), stream);
  tasnet_persistent<<<dim3(NBLK), dim3(NTHR), 0, stream>>>(hp);
}

// Round 10
// 1030.978 us; speedup vs baseline: 6.7164x; 2.9041x over previous
//
#include <hip/hip_runtime.h>
#include <cstddef>

#define T_     8000
#define L_     803
#define C_     256
#define D_     512
#define NB_    32
#define FK_    20
#define NBATCH 4
#define EPS_   1e-5f

#define NBLK   52            // 13 l-tiles x 4 batch; one block owns full C/D of a strip
#define NTHR   512           // 8 waves
#define NTH_G  (NBLK * NTHR)
#define SG     1040          // LDS k-group stride bytes: 64 cols * 16B + 16B pad

typedef __attribute__((ext_vector_type(8))) short bf16x8;
typedef __attribute__((ext_vector_type(4))) short shortx4;
typedef __attribute__((ext_vector_type(4))) float f32x4;

__device__ __forceinline__ short f2bf(float x) {
  unsigned u = __float_as_uint(x);
  u += 0x7FFF + ((u >> 16) & 1);   // RNE
  return (short)(u >> 16);
}
__device__ __forceinline__ float bf2f(short u) {
  return __uint_as_float(((unsigned)(unsigned short)u) << 16);
}

struct __align__(64) Bar { unsigned cnt; unsigned phase; unsigned pad[14]; };

__device__ __forceinline__ void bar_heavy(Bar* b, unsigned nblk, int tid) {
  __syncthreads();
  if (tid == 0) {
    __threadfence();
    unsigned ph = __hip_atomic_load(&b->phase, __ATOMIC_RELAXED, __HIP_MEMORY_SCOPE_AGENT);
    unsigned prev = __hip_atomic_fetch_add(&b->cnt, 1u, __ATOMIC_RELAXED, __HIP_MEMORY_SCOPE_AGENT);
    if (prev == nblk - 1) {
      __hip_atomic_store(&b->cnt, 0u, __ATOMIC_RELAXED, __HIP_MEMORY_SCOPE_AGENT);
      __hip_atomic_store(&b->phase, ph + 1u, __ATOMIC_RELEASE, __HIP_MEMORY_SCOPE_AGENT);
    } else {
      while (__hip_atomic_load(&b->phase, __ATOMIC_RELAXED, __HIP_MEMORY_SCOPE_AGENT) == ph)
        __builtin_amdgcn_s_sleep(2);
    }
    __threadfence();
  }
  __syncthreads();
}

struct KParams {
  const float *x, *w_enc, *w1, *wd, *w2, *w_dec;
  const float *g1, *bb1, *m1, *v1;
  const float *g2, *bb2, *m2, *v2;
  const float *g3, *bb3, *m3, *v3;
  float *out;
  float *s1, *o1, *s2, *o2, *s3, *o3;
  float *yb;                  // y [n][l][c] f32
  short *w1b, *w2b;           // bf16 weights
  unsigned short *zg;         // z publish: [layer][blk][64][512] bf16 (rotated)
  unsigned *ct;               // per-block monotone layer counter [52]
  Bar *gbar;
};

__global__ __launch_bounds__(NTHR, 2) void tasnet_fused(KParams p) {
  const int tid = threadIdx.x;
  const int bid = blockIdx.x;
  const int gtid = bid * NTHR + tid;

  const int xt = bid % 13, n = bid / 13;
  const int l0 = xt * 64;

  const int lane = tid & 63, wv = tid >> 6;
  const int frow = lane & 15, kg = lane >> 4;

  __shared__ __align__(16) char BsRaw[64 * SG];   // 66560 B (B1: kgrp 0..31; B3: 0..63)
  __shared__ __align__(16) char ZsRaw[64 * SG];   // z tile [dgrp][col][8] bf16

  // ---------------- phase 0: BN fold + weight bf16 cvt ----------------
  for (int i = gtid; i < NB_ * C_; i += NTH_G) {
    float s = p.g1[i] * rsqrtf(p.v1[i] + EPS_);
    p.s1[i] = s; p.o1[i] = p.bb1[i] - p.m1[i] * s;
  }
  for (int i = gtid; i < NB_ * D_; i += NTH_G) {
    float s2 = p.g2[i] * rsqrtf(p.v2[i] + EPS_);
    p.s2[i] = s2; p.o2[i] = p.bb2[i] - p.m2[i] * s2;
    float s3 = p.g3[i] * rsqrtf(p.v3[i] + EPS_);
    p.s3[i] = s3; p.o3[i] = p.bb3[i] - p.m3[i] * s3;
  }
  for (int i = gtid; i < NB_ * D_ * C_ / 4; i += NTH_G) {
    float4 a = ((const float4*)p.w1)[i];
    float4 b = ((const float4*)p.w2)[i];
    shortx4 sa, sb;
    sa[0] = f2bf(a.x); sa[1] = f2bf(a.y); sa[2] = f2bf(a.z); sa[3] = f2bf(a.w);
    sb[0] = f2bf(b.x); sb[1] = f2bf(b.y); sb[2] = f2bf(b.z); sb[3] = f2bf(b.w);
    *(shortx4*)&p.w1b[4 * i] = sa;
    *(shortx4*)&p.w2b[4 * i] = sb;
  }

  // ---------------- encoder -> registers (h and xe never hit memory) ----
  // element (ia,jb,jj): c = wv*32+ia*16+kg*4+jj ; l = l0 + jb*16 + frow
  f32x4 hreg[2][4], xer[2][4];
  {
    const float* xn = p.x + (size_t)n * T_;
#pragma unroll
    for (int jb = 0; jb < 4; ++jb) {
      int gl = l0 + jb * 16 + frow;
      int t0 = gl * 10 - 20;
      float xw[FK_];
#pragma unroll
      for (int k = 0; k < FK_; ++k) {
        int t = t0 + k;
        xw[k] = (t >= 0 && t < T_) ? xn[t] : 0.f;
      }
#pragma unroll
      for (int ia = 0; ia < 2; ++ia) {
#pragma unroll
        for (int jj = 0; jj < 4; ++jj) {
          int c = wv * 32 + ia * 16 + kg * 4 + jj;
          const float* w = p.w_enc + c * FK_;
          float acc = 0.f;
#pragma unroll
          for (int k = 0; k < FK_; ++k) acc = fmaf(xw[k], w[k], acc);
          hreg[ia][jb][jj] = acc;
          xer[ia][jb][jj] = acc;
        }
      }
    }
  }
  bar_heavy(p.gbar, NBLK, tid);   // publish params + bf16 weights

  // ---------------- 32 residual blocks, fully fused ----------------
  for (int layer = 0; layer < NB_; ++layer) {
    const int dil = 1 << (layer & 7);
    const float* s1p = p.s1 + layer * C_;
    const float* o1p = p.o1 + layer * C_;
    const float* s2p = p.s2 + layer * D_;
    const float* o2p = p.o2 + layer * D_;
    const float* s3p = p.s3 + layer * D_;
    const float* o3p = p.o3 + layer * D_;

    // ===== B1 = BN1(hreg) -> Bs (bf16 [kgrp][col][8]) =====
#pragma unroll
    for (int ia = 0; ia < 2; ++ia) {
      int cb = wv * 32 + ia * 16 + kg * 4;
      float4 s1v = *(const float4*)(s1p + cb);
      float4 o1v = *(const float4*)(o1p + cb);
#pragma unroll
      for (int jb = 0; jb < 4; ++jb) {
        shortx4 pk;
        pk[0] = f2bf(fmaf(hreg[ia][jb][0], s1v.x, o1v.x));
        pk[1] = f2bf(fmaf(hreg[ia][jb][1], s1v.y, o1v.y));
        pk[2] = f2bf(fmaf(hreg[ia][jb][2], s1v.z, o1v.z));
        pk[3] = f2bf(fmaf(hreg[ia][jb][3], s1v.w, o1v.w));
        *(shortx4*)(BsRaw + (cb >> 3) * SG + (jb * 16 + frow) * 16 + (kg & 1) * 8) = pk;
      }
    }
    __syncthreads();

    // ===== stage1 MFMA: acc1[d 512][l 64] ; wave owns 64 d rows =====
    f32x4 acc1[4][4] = {};
    {
      const short* W1 = p.w1b + (size_t)layer * D_ * C_;
#pragma unroll
      for (int k0 = 0; k0 < 8; ++k0) {
        int kb = k0 * 32 + kg * 8;
        bf16x8 bfr[4];
#pragma unroll
        for (int jb = 0; jb < 4; ++jb)
          bfr[jb] = *(bf16x8*)(BsRaw + (k0 * 4 + kg) * SG + (jb * 16 + frow) * 16);
#pragma unroll
        for (int ia = 0; ia < 4; ++ia) {
          bf16x8 af = *(const bf16x8*)(W1 + (size_t)(wv * 64 + ia * 16 + frow) * C_ + kb);
#pragma unroll
          for (int jb = 0; jb < 4; ++jb)
            acc1[ia][jb] = __builtin_amdgcn_mfma_f32_16x16x32_bf16(af, bfr[jb], acc1[ia][jb], 0, 0, 0);
        }
      }
    }

    // ===== z = BN2(acc1) -> zLds + sc1 publish for neighbors =====
    {
      unsigned short* zgl = p.zg + ((size_t)(layer * NBLK + bid)) * (64 * 512);
#pragma unroll
      for (int ia = 0; ia < 4; ++ia) {
        int db = wv * 64 + ia * 16 + kg * 4;
        float4 s2v = *(const float4*)(s2p + db);
        float4 o2v = *(const float4*)(o2p + db);
#pragma unroll
        for (int jb = 0; jb < 4; ++jb) {
          int l = jb * 16 + frow;
          shortx4 pk;
          pk[0] = f2bf(fmaf(acc1[ia][jb][0], s2v.x, o2v.x));
          pk[1] = f2bf(fmaf(acc1[ia][jb][1], s2v.y, o2v.y));
          pk[2] = f2bf(fmaf(acc1[ia][jb][2], s2v.z, o2v.z));
          pk[3] = f2bf(fmaf(acc1[ia][jb][3], s2v.w, o2v.w));
          *(shortx4*)(ZsRaw + (db >> 3) * SG + l * 16 + (kg & 1) * 8) = pk;
          unsigned long long u;
          __builtin_memcpy(&u, &pk, 8);
          __hip_atomic_store((unsigned long long*)(zgl + (size_t)l * 512 + db), u,
                             __ATOMIC_RELAXED, __HIP_MEMORY_SCOPE_AGENT);
        }
      }
    }
    __syncthreads();   // zLds complete; all waves' sc1 publishes drained
    if (tid == 0)
      __hip_atomic_store(&p.ct[bid], (unsigned)(layer + 1),
                         __ATOMIC_RELAXED, __HIP_MEMORY_SCOPE_AGENT);
    // wait for neighbor strips' z (wavefront sync, no global barrier)
    {
      int delta = (dil + 63) >> 6;   // 1 for dil<=64, 2 for dil=128
      if (tid == 0) {
        for (int xx = xt - delta; xx <= xt + delta; ++xx) {
          if (xx < 0 || xx > 12 || xx == xt) continue;
          const unsigned* c2 = &p.ct[n * 13 + xx];
          while (__hip_atomic_load((unsigned*)c2, __ATOMIC_RELAXED, __HIP_MEMORY_SCOPE_AGENT)
                 <= (unsigned)layer)
            __builtin_amdgcn_s_sleep(1);
        }
      }
      __syncthreads();
    }

    // ===== B3 = BN3(dconv(z)) -> Bs ; wave handles 8 rows, lane owns 8 d =====
    {
      const float* wdp = p.wd + (size_t)layer * D_ * 3 + lane * 24;
      float4 wq[6];
#pragma unroll
      for (int q = 0; q < 6; ++q) wq[q] = *(const float4*)(wdp + 4 * q);
      float4 s3a = *(const float4*)(s3p + lane * 8), s3b = *(const float4*)(s3p + lane * 8 + 4);
      float4 o3a = *(const float4*)(o3p + lane * 8), o3b = *(const float4*)(o3p + lane * 8 + 4);
      const unsigned short* zlay = p.zg + (size_t)layer * NBLK * (64 * 512);
#pragma unroll
      for (int r = 0; r < 8; ++r) {
        int row = wv * 8 + r;
        int gcol = l0 + row;
        bf16x8 zc = *(bf16x8*)(ZsRaw + lane * SG + row * 16);
        bf16x8 zl = {0, 0, 0, 0, 0, 0, 0, 0};
        bf16x8 zr = {0, 0, 0, 0, 0, 0, 0, 0};
        int gl = gcol - dil;
        if (gl >= 0) {
          int xl = gl >> 6;
          if (xl == xt) zl = *(bf16x8*)(ZsRaw + lane * SG + (gl - l0) * 16);
          else zl = *(const bf16x8*)(zlay + ((size_t)(n * 13 + xl)) * (64 * 512)
                                     + (size_t)(gl & 63) * 512 + lane * 8);
        }
        int gr = gcol + dil;
        if (gr < L_) {
          int xr = gr >> 6;
          if (xr == xt) zr = *(bf16x8*)(ZsRaw + lane * SG + (gr - l0) * 16);
          else zr = *(const bf16x8*)(zlay + ((size_t)(n * 13 + xr)) * (64 * 512)
                                     + (size_t)(gr & 63) * 512 + lane * 8);
        }
        bf16x8 pb;
#pragma unroll
        for (int j = 0; j < 8; ++j) {
          float w0 = wq[(3 * j + 0) >> 2][(3 * j + 0) & 3];
          float w1v = wq[(3 * j + 1) >> 2][(3 * j + 1) & 3];
          float w2v = wq[(3 * j + 2) >> 2][(3 * j + 2) & 3];
          float m = bf2f(zc[j]) * w1v;
          m = fmaf(bf2f(zl[j]), w0, m);
          m = fmaf(bf2f(zr[j]), w2v, m);
          float s3v = (j < 4) ? s3a[j] : s3b[j - 4];
          float o3v = (j < 4) ? o3a[j] : o3b[j - 4];
          pb[j] = f2bf(fmaf(m, s3v, o3v));
        }
        *(bf16x8*)(BsRaw + lane * SG + row * 16) = pb;
      }
    }
    __syncthreads();

    // ===== stage2 MFMA: acc2[c 256][l 64] ; hreg += =====
    {
      f32x4 acc2[2][4] = {};
      const short* W2 = p.w2b + (size_t)layer * C_ * D_;
#pragma unroll
      for (int k0 = 0; k0 < 16; ++k0) {
        int kb = k0 * 32 + kg * 8;
        bf16x8 bfr[4];
#pragma unroll
        for (int jb = 0; jb < 4; ++jb)
          bfr[jb] = *(bf16x8*)(BsRaw + (k0 * 4 + kg) * SG + (jb * 16 + frow) * 16);
#pragma unroll
        for (int ia = 0; ia < 2; ++ia) {
          bf16x8 af = *(const bf16x8*)(W2 + (size_t)(wv * 32 + ia * 16 + frow) * D_ + kb);
#pragma unroll
          for (int jb = 0; jb < 4; ++jb)
            acc2[ia][jb] = __builtin_amdgcn_mfma_f32_16x16x32_bf16(af, bfr[jb], acc2[ia][jb], 0, 0, 0);
        }
      }
#pragma unroll
      for (int ia = 0; ia < 2; ++ia)
#pragma unroll
        for (int jb = 0; jb < 4; ++jb)
#pragma unroll
          for (int jj = 0; jj < 4; ++jj)
            hreg[ia][jb][jj] += acc2[ia][jb][jj];
    }
    __syncthreads();   // Bs reads done before next layer's B1 writes
  }

  // ---------------- mask: y = xe * sigmoid(h) -> yb [n][l][c] ----------------
  {
    float* yn = p.yb + (size_t)n * ((size_t)L_ * C_);
#pragma unroll
    for (int ia = 0; ia < 2; ++ia) {
      int cb = wv * 32 + ia * 16 + kg * 4;
#pragma unroll
      for (int jb = 0; jb < 4; ++jb) {
        int gl = l0 + jb * 16 + frow;
        if (gl < L_) {
          float v[4];
#pragma unroll
          for (int jj = 0; jj < 4; ++jj)
            v[jj] = xer[ia][jb][jj] / (1.f + expf(-hreg[ia][jb][jj]));
          unsigned long long u0, u1;
          __builtin_memcpy(&u0, &v[0], 8);
          __builtin_memcpy(&u1, &v[2], 8);
          unsigned long long* dst = (unsigned long long*)(yn + (size_t)gl * C_ + cb);
          __hip_atomic_store(dst + 0, u0, __ATOMIC_RELAXED, __HIP_MEMORY_SCOPE_AGENT);
          __hip_atomic_store(dst + 1, u1, __ATOMIC_RELAXED, __HIP_MEMORY_SCOPE_AGENT);
        }
      }
    }
  }
  bar_heavy(p.gbar, NBLK, tid);

  // ---------------- decoder ----------------
  for (int idx = gtid; idx < NBATCH * T_; idx += NTH_G) {
    int t = idx % T_;
    int nn = idx / T_;
    int tt = t + FK_;
    int lq = tt / 10;      // in [2, 801]
    int k0 = tt % 10;
    const float* y0 = p.yb + (size_t)nn * ((size_t)L_ * C_) + (size_t)lq * C_;
    const float* y1 = y0 - C_;
    float acc = 0.f;
#pragma unroll 8
    for (int c = 0; c < C_; c++) {
      const float* wr2 = p.w_dec + c * FK_;
      acc = fmaf(y0[c], wr2[k0], acc);
      acc = fmaf(y1[c], wr2[k0 + 10], acc);
    }
    p.out[idx] = acc;
  }
}

extern "C" void kernel_launch(void* const* d_in, const int* in_sizes, int n_in,
                              void* d_out, int out_size, void* d_ws, size_t ws_size,
                              hipStream_t stream) {
  KParams hp;
  hp.x     = (const float*)d_in[0];
  hp.w_enc = (const float*)d_in[1];
  hp.w1    = (const float*)d_in[2];
  hp.wd    = (const float*)d_in[3];
  hp.w2    = (const float*)d_in[4];
  hp.w_dec = (const float*)d_in[5];
  hp.g1 = (const float*)d_in[6];  hp.bb1 = (const float*)d_in[7];
  hp.m1 = (const float*)d_in[8];  hp.v1  = (const float*)d_in[9];
  hp.g2 = (const float*)d_in[10]; hp.bb2 = (const float*)d_in[11];
  hp.m2 = (const float*)d_in[12]; hp.v2  = (const float*)d_in[13];
  hp.g3 = (const float*)d_in[14]; hp.bb3 = (const float*)d_in[15];
  hp.m3 = (const float*)d_in[16]; hp.v3  = (const float*)d_in[17];
  hp.out = (float*)d_out;

  char* cur = (char*)d_ws;
  auto take = [&](size_t bytes) { char* r = cur; cur += (bytes + 255) & ~(size_t)255; return r; };
  hp.gbar = (Bar*)take(256);
  hp.ct   = (unsigned*)take(NBLK * 4);
  hp.s1 = (float*)take(NB_ * C_ * 4);
  hp.o1 = (float*)take(NB_ * C_ * 4);
  hp.s2 = (float*)take(NB_ * D_ * 4);
  hp.o2 = (float*)take(NB_ * D_ * 4);
  hp.s3 = (float*)take(NB_ * D_ * 4);
  hp.o3 = (float*)take(NB_ * D_ * 4);
  hp.yb  = (float*)take((size_t)NBATCH * L_ * C_ * 4);
  hp.w1b = (short*)take((size_t)NB_ * D_ * C_ * 2);
  hp.w2b = (short*)take((size_t)NB_ * D_ * C_ * 2);
  hp.zg  = (unsigned short*)take((size_t)NB_ * NBLK * 64 * 512 * 2);   // 109 MB

  hipMemsetAsync(d_ws, 0, 1024, stream);   // gbar + ct
  tasnet_fused<<<dim3(NBLK), dim3(NTHR), 0, stream>>>(hp);
}

// Round 11
// 938.483 us; speedup vs baseline: 7.3783x; 1.0986x over previous
//
#include <hip/hip_runtime.h>
#include <cstddef>

#define T_     8000
#define L_     803
#define C_     256
#define D_     512
#define NB_    32
#define FK_    20
#define NBATCH 4
#define EPS_   1e-5f

#define NBLK   52            // 13 l-tiles x 4 batch; one block owns full C/D of a strip
#define NTHR   512           // 8 waves
#define NTH_G  (NBLK * NTHR)
#define SG     1040          // LDS k-group stride bytes: 64 cols * 16B + 16B pad

typedef __attribute__((ext_vector_type(8))) short bf16x8;
typedef __attribute__((ext_vector_type(4))) short shortx4;
typedef __attribute__((ext_vector_type(4))) float f32x4;

__device__ __forceinline__ short f2bf(float x) {
  unsigned u = __float_as_uint(x);
  u += 0x7FFF + ((u >> 16) & 1);   // RNE
  return (short)(u >> 16);
}
__device__ __forceinline__ float bf2f(short u) {
  return __uint_as_float(((unsigned)(unsigned short)u) << 16);
}

struct __align__(64) Bar { unsigned cnt; unsigned phase; unsigned pad[14]; };

__device__ __forceinline__ void bar_heavy(Bar* b, unsigned nblk, int tid) {
  __syncthreads();
  if (tid == 0) {
    __threadfence();
    unsigned ph = __hip_atomic_load(&b->phase, __ATOMIC_RELAXED, __HIP_MEMORY_SCOPE_AGENT);
    unsigned prev = __hip_atomic_fetch_add(&b->cnt, 1u, __ATOMIC_RELAXED, __HIP_MEMORY_SCOPE_AGENT);
    if (prev == nblk - 1) {
      __hip_atomic_store(&b->cnt, 0u, __ATOMIC_RELAXED, __HIP_MEMORY_SCOPE_AGENT);
      __hip_atomic_store(&b->phase, ph + 1u, __ATOMIC_RELEASE, __HIP_MEMORY_SCOPE_AGENT);
    } else {
      while (__hip_atomic_load(&b->phase, __ATOMIC_RELAXED, __HIP_MEMORY_SCOPE_AGENT) == ph)
        __builtin_amdgcn_s_sleep(2);
    }
    __threadfence();
  }
  __syncthreads();
}

struct KParams {
  const float *x, *w_enc, *w1, *wd, *w2, *w_dec;
  const float *g1, *bb1, *m1, *v1;
  const float *g2, *bb2, *m2, *v2;
  const float *g3, *bb3, *m3, *v3;
  float *out;
  float *s1, *o1, *s2, *o2, *s3, *o3;
  float *yb;                  // y [n][l][c] f32
  short *w1b, *w2b;           // bf16 weights
  unsigned short *zg;         // z publish: [layer][blk][64][512] bf16 (rotated)
  unsigned *ct;               // per-block monotone layer counter [52]
  Bar *gbar;
};

// ---------- full-grid prep: BN fold + weight bf16 conversion ----------
__global__ __launch_bounds__(256) void prep_kernel(KParams p) {
  const int gtid = blockIdx.x * 256 + threadIdx.x;
  const int stride = gridDim.x * 256;
  for (int i = gtid; i < NB_ * C_; i += stride) {
    float s = p.g1[i] * rsqrtf(p.v1[i] + EPS_);
    p.s1[i] = s; p.o1[i] = p.bb1[i] - p.m1[i] * s;
  }
  for (int i = gtid; i < NB_ * D_; i += stride) {
    float s2 = p.g2[i] * rsqrtf(p.v2[i] + EPS_);
    p.s2[i] = s2; p.o2[i] = p.bb2[i] - p.m2[i] * s2;
    float s3 = p.g3[i] * rsqrtf(p.v3[i] + EPS_);
    p.s3[i] = s3; p.o3[i] = p.bb3[i] - p.m3[i] * s3;
  }
  for (int i = gtid; i < NB_ * D_ * C_ / 4; i += stride) {
    float4 a = ((const float4*)p.w1)[i];
    float4 b = ((const float4*)p.w2)[i];
    shortx4 sa, sb;
    sa[0] = f2bf(a.x); sa[1] = f2bf(a.y); sa[2] = f2bf(a.z); sa[3] = f2bf(a.w);
    sb[0] = f2bf(b.x); sb[1] = f2bf(b.y); sb[2] = f2bf(b.z); sb[3] = f2bf(b.w);
    *(shortx4*)&p.w1b[4 * i] = sa;
    *(shortx4*)&p.w2b[4 * i] = sb;
  }
}

__global__ __launch_bounds__(NTHR, 2) void tasnet_fused(KParams p) {
  const int tid = threadIdx.x;
  const int bid = blockIdx.x;
  const int gtid = bid * NTHR + tid;

  const int xt = bid % 13, n = bid / 13;
  const int l0 = xt * 64;

  const int lane = tid & 63, wv = tid >> 6;
  const int frow = lane & 15, kg = lane >> 4;

  __shared__ __align__(16) char BsRaw[64 * SG];   // 66560 B
  __shared__ __align__(16) char ZsRaw[64 * SG];   // z tile [dgrp][col][8] bf16

  // ---------------- encoder -> registers (h and xe never hit memory) ----
  f32x4 hreg[2][4], xer[2][4];
  {
    const float* xn = p.x + (size_t)n * T_;
#pragma unroll
    for (int jb = 0; jb < 4; ++jb) {
      int gl = l0 + jb * 16 + frow;
      int t0 = gl * 10 - 20;
      float xw[FK_];
#pragma unroll
      for (int k = 0; k < FK_; ++k) {
        int t = t0 + k;
        xw[k] = (t >= 0 && t < T_) ? xn[t] : 0.f;
      }
#pragma unroll
      for (int ia = 0; ia < 2; ++ia) {
#pragma unroll
        for (int jj = 0; jj < 4; ++jj) {
          int c = wv * 32 + ia * 16 + kg * 4 + jj;
          const float* w = p.w_enc + c * FK_;
          float acc = 0.f;
#pragma unroll
          for (int k = 0; k < FK_; ++k) acc = fmaf(xw[k], w[k], acc);
          hreg[ia][jb][jj] = acc;
          xer[ia][jb][jj] = acc;
        }
      }
    }
  }

  // ---------------- 32 residual blocks, fully fused ----------------
  for (int layer = 0; layer < NB_; ++layer) {
    const int dil = 1 << (layer & 7);
    const float* s1p = p.s1 + layer * C_;
    const float* o1p = p.o1 + layer * C_;
    const float* s2p = p.s2 + layer * D_;
    const float* o2p = p.o2 + layer * D_;
    const float* s3p = p.s3 + layer * D_;
    const float* o3p = p.o3 + layer * D_;

    // ===== B1 = BN1(hreg) -> Bs =====
#pragma unroll
    for (int ia = 0; ia < 2; ++ia) {
      int cb = wv * 32 + ia * 16 + kg * 4;
      float4 s1v = *(const float4*)(s1p + cb);
      float4 o1v = *(const float4*)(o1p + cb);
#pragma unroll
      for (int jb = 0; jb < 4; ++jb) {
        shortx4 pk;
        pk[0] = f2bf(fmaf(hreg[ia][jb][0], s1v.x, o1v.x));
        pk[1] = f2bf(fmaf(hreg[ia][jb][1], s1v.y, o1v.y));
        pk[2] = f2bf(fmaf(hreg[ia][jb][2], s1v.z, o1v.z));
        pk[3] = f2bf(fmaf(hreg[ia][jb][3], s1v.w, o1v.w));
        *(shortx4*)(BsRaw + (cb >> 3) * SG + (jb * 16 + frow) * 16 + (kg & 1) * 8) = pk;
      }
    }
    __syncthreads();

    // ===== stage1 MFMA: acc1[d 512][l 64] ; wave owns 64 d rows =====
    f32x4 acc1[4][4] = {};
    {
      const short* W1 = p.w1b + (size_t)layer * D_ * C_;
#pragma unroll
      for (int k0 = 0; k0 < 8; ++k0) {
        int kb = k0 * 32 + kg * 8;
        bf16x8 bfr[4];
#pragma unroll
        for (int jb = 0; jb < 4; ++jb)
          bfr[jb] = *(bf16x8*)(BsRaw + (k0 * 4 + kg) * SG + (jb * 16 + frow) * 16);
#pragma unroll
        for (int ia = 0; ia < 4; ++ia) {
          bf16x8 af = *(const bf16x8*)(W1 + (size_t)(wv * 64 + ia * 16 + frow) * C_ + kb);
#pragma unroll
          for (int jb = 0; jb < 4; ++jb)
            acc1[ia][jb] = __builtin_amdgcn_mfma_f32_16x16x32_bf16(af, bfr[jb], acc1[ia][jb], 0, 0, 0);
        }
      }
    }

    // ===== z = BN2(acc1) -> zLds + sc1 publish (HALO COLUMNS ONLY) =====
    {
      const int w = (dil < 64) ? dil : 64;   // halo width each side
      unsigned short* zgl = p.zg + ((size_t)(layer * NBLK + bid)) * (64 * 512);
#pragma unroll
      for (int ia = 0; ia < 4; ++ia) {
        int db = wv * 64 + ia * 16 + kg * 4;
        float4 s2v = *(const float4*)(s2p + db);
        float4 o2v = *(const float4*)(o2p + db);
#pragma unroll
        for (int jb = 0; jb < 4; ++jb) {
          int l = jb * 16 + frow;
          shortx4 pk;
          pk[0] = f2bf(fmaf(acc1[ia][jb][0], s2v.x, o2v.x));
          pk[1] = f2bf(fmaf(acc1[ia][jb][1], s2v.y, o2v.y));
          pk[2] = f2bf(fmaf(acc1[ia][jb][2], s2v.z, o2v.z));
          pk[3] = f2bf(fmaf(acc1[ia][jb][3], s2v.w, o2v.w));
          *(shortx4*)(ZsRaw + (db >> 3) * SG + l * 16 + (kg & 1) * 8) = pk;
          if (l < w || l >= 64 - w) {
            unsigned long long u;
            __builtin_memcpy(&u, &pk, 8);
            __hip_atomic_store((unsigned long long*)(zgl + (size_t)l * 512 + db), u,
                               __ATOMIC_RELAXED, __HIP_MEMORY_SCOPE_AGENT);
          }
        }
      }
    }
    __syncthreads();   // zLds complete; sc1 publishes drained (vmcnt at s_barrier)
    if (tid == 0)
      __hip_atomic_store(&p.ct[bid], (unsigned)(layer + 1),
                         __ATOMIC_RELAXED, __HIP_MEMORY_SCOPE_AGENT);

    // ===== B3 = BN3(dconv(z)) two-pass: interior first, edges after spin =====
    {
      const float* wdp = p.wd + (size_t)layer * D_ * 3 + lane * 24;
      float4 wq[6];
#pragma unroll
      for (int q = 0; q < 6; ++q) wq[q] = *(const float4*)(wdp + 4 * q);
      float4 s3a = *(const float4*)(s3p + lane * 8), s3b = *(const float4*)(s3p + lane * 8 + 4);
      float4 o3a = *(const float4*)(o3p + lane * 8), o3b = *(const float4*)(o3p + lane * 8 + 4);
      const unsigned short* zlay = p.zg + (size_t)layer * NBLK * (64 * 512);

#pragma unroll
      for (int pass = 0; pass < 2; ++pass) {
        if (pass == 1) {
          // spin for neighbors' z (only the strips we actually read)
          if (tid == 0) {
            int step = (dil <= 64) ? 1 : 2;
            for (int s = -1; s <= 1; s += 2) {
              int xx = xt + s * step;
              if (xx < 0 || xx > 12) continue;
              const unsigned* c2 = &p.ct[n * 13 + xx];
              while (__hip_atomic_load((unsigned*)c2, __ATOMIC_RELAXED, __HIP_MEMORY_SCOPE_AGENT)
                     <= (unsigned)layer)
                __builtin_amdgcn_s_sleep(1);
            }
          }
          __syncthreads();
        }
#pragma unroll
        for (int r = 0; r < 8; ++r) {
          int row = wv * 8 + r;
          int gcol = l0 + row;
          int gl = gcol - dil, gr = gcol + dil;
          bool remL = (gl >= 0) && (gl < l0);
          bool remR = (gr < L_) && (gr >= l0 + 64);
          bool isRem = remL || remR;
          if ((pass == 0) == isRem) continue;
          bf16x8 zc = *(bf16x8*)(ZsRaw + lane * SG + row * 16);
          bf16x8 zl = {0, 0, 0, 0, 0, 0, 0, 0};
          bf16x8 zr = {0, 0, 0, 0, 0, 0, 0, 0};
          if (gl >= 0) {
            if (!remL) zl = *(bf16x8*)(ZsRaw + lane * SG + (gl - l0) * 16);
            else zl = *(const bf16x8*)(zlay + ((size_t)(n * 13 + (gl >> 6))) * (64 * 512)
                                       + (size_t)(gl & 63) * 512 + lane * 8);
          }
          if (gr < L_) {
            if (!remR) zr = *(bf16x8*)(ZsRaw + lane * SG + (gr - l0) * 16);
            else zr = *(const bf16x8*)(zlay + ((size_t)(n * 13 + (gr >> 6))) * (64 * 512)
                                       + (size_t)(gr & 63) * 512 + lane * 8);
          }
          bf16x8 pb;
#pragma unroll
          for (int j = 0; j < 8; ++j) {
            float w0 = wq[(3 * j + 0) >> 2][(3 * j + 0) & 3];
            float w1v = wq[(3 * j + 1) >> 2][(3 * j + 1) & 3];
            float w2v = wq[(3 * j + 2) >> 2][(3 * j + 2) & 3];
            float m = bf2f(zc[j]) * w1v;
            m = fmaf(bf2f(zl[j]), w0, m);
            m = fmaf(bf2f(zr[j]), w2v, m);
            float s3v = (j < 4) ? s3a[j] : s3b[j - 4];
            float o3v = (j < 4) ? o3a[j] : o3b[j - 4];
            pb[j] = f2bf(fmaf(m, s3v, o3v));
          }
          *(bf16x8*)(BsRaw + lane * SG + row * 16) = pb;
        }
      }
    }
    __syncthreads();

    // ===== stage2 MFMA: acc2[c 256][l 64] ; hreg += =====
    {
      f32x4 acc2[2][4] = {};
      const short* W2 = p.w2b + (size_t)layer * C_ * D_;
#pragma unroll
      for (int k0 = 0; k0 < 16; ++k0) {
        int kb = k0 * 32 + kg * 8;
        bf16x8 bfr[4];
#pragma unroll
        for (int jb = 0; jb < 4; ++jb)
          bfr[jb] = *(bf16x8*)(BsRaw + (k0 * 4 + kg) * SG + (jb * 16 + frow) * 16);
#pragma unroll
        for (int ia = 0; ia < 2; ++ia) {
          bf16x8 af = *(const bf16x8*)(W2 + (size_t)(wv * 32 + ia * 16 + frow) * D_ + kb);
#pragma unroll
          for (int jb = 0; jb < 4; ++jb)
            acc2[ia][jb] = __builtin_amdgcn_mfma_f32_16x16x32_bf16(af, bfr[jb], acc2[ia][jb], 0, 0, 0);
        }
      }
#pragma unroll
      for (int ia = 0; ia < 2; ++ia)
#pragma unroll
        for (int jb = 0; jb < 4; ++jb)
#pragma unroll
          for (int jj = 0; jj < 4; ++jj)
            hreg[ia][jb][jj] += acc2[ia][jb][jj];
    }
    __syncthreads();   // Bs reads done before next layer's B1 writes
  }

  // ---------------- mask: y = xe * sigmoid(h) -> yb [n][l][c] ----------------
  {
    float* yn = p.yb + (size_t)n * ((size_t)L_ * C_);
#pragma unroll
    for (int ia = 0; ia < 2; ++ia) {
      int cb = wv * 32 + ia * 16 + kg * 4;
#pragma unroll
      for (int jb = 0; jb < 4; ++jb) {
        int gl = l0 + jb * 16 + frow;
        if (gl < L_) {
          float v[4];
#pragma unroll
          for (int jj = 0; jj < 4; ++jj)
            v[jj] = xer[ia][jb][jj] / (1.f + expf(-hreg[ia][jb][jj]));
          unsigned long long u0, u1;
          __builtin_memcpy(&u0, &v[0], 8);
          __builtin_memcpy(&u1, &v[2], 8);
          unsigned long long* dst = (unsigned long long*)(yn + (size_t)gl * C_ + cb);
          __hip_atomic_store(dst + 0, u0, __ATOMIC_RELAXED, __HIP_MEMORY_SCOPE_AGENT);
          __hip_atomic_store(dst + 1, u1, __ATOMIC_RELAXED, __HIP_MEMORY_SCOPE_AGENT);
        }
      }
    }
  }
  bar_heavy(p.gbar, NBLK, tid);

  // ---------------- decoder ----------------
  for (int idx = gtid; idx < NBATCH * T_; idx += NTH_G) {
    int t = idx % T_;
    int nn = idx / T_;
    int tt = t + FK_;
    int lq = tt / 10;      // in [2, 801]
    int k0 = tt % 10;
    const float* y0 = p.yb + (size_t)nn * ((size_t)L_ * C_) + (size_t)lq * C_;
    const float* y1 = y0 - C_;
    float acc = 0.f;
#pragma unroll 8
    for (int c = 0; c < C_; c++) {
      const float* wr2 = p.w_dec + c * FK_;
      acc = fmaf(y0[c], wr2[k0], acc);
      acc = fmaf(y1[c], wr2[k0 + 10], acc);
    }
    p.out[idx] = acc;
  }
}

extern "C" void kernel_launch(void* const* d_in, const int* in_sizes, int n_in,
                              void* d_out, int out_size, void* d_ws, size_t ws_size,
                              hipStream_t stream) {
  KParams hp;
  hp.x     = (const float*)d_in[0];
  hp.w_enc = (const float*)d_in[1];
  hp.w1    = (const float*)d_in[2];
  hp.wd    = (const float*)d_in[3];
  hp.w2    = (const float*)d_in[4];
  hp.w_dec = (const float*)d_in[5];
  hp.g1 = (const float*)d_in[6];  hp.bb1 = (const float*)d_in[7];
  hp.m1 = (const float*)d_in[8];  hp.v1  = (const float*)d_in[9];
  hp.g2 = (const float*)d_in[10]; hp.bb2 = (const float*)d_in[11];
  hp.m2 = (const float*)d_in[12]; hp.v2  = (const float*)d_in[13];
  hp.g3 = (const float*)d_in[14]; hp.bb3 = (const float*)d_in[15];
  hp.m3 = (const float*)d_in[16]; hp.v3  = (const float*)d_in[17];
  hp.out = (float*)d_out;

  char* cur = (char*)d_ws;
  auto take = [&](size_t bytes) { char* r = cur; cur += (bytes + 255) & ~(size_t)255; return r; };
  hp.gbar = (Bar*)take(256);
  hp.ct   = (unsigned*)take(NBLK * 4);
  hp.s1 = (float*)take(NB_ * C_ * 4);
  hp.o1 = (float*)take(NB_ * C_ * 4);
  hp.s2 = (float*)take(NB_ * D_ * 4);
  hp.o2 = (float*)take(NB_ * D_ * 4);
  hp.s3 = (float*)take(NB_ * D_ * 4);
  hp.o3 = (float*)take(NB_ * D_ * 4);
  hp.yb  = (float*)take((size_t)NBATCH * L_ * C_ * 4);
  hp.w1b = (short*)take((size_t)NB_ * D_ * C_ * 2);
  hp.w2b = (short*)take((size_t)NB_ * D_ * C_ * 2);
  hp.zg  = (unsigned short*)take((size_t)NB_ * NBLK * 64 * 512 * 2);   // 109 MB

  hipMemsetAsync(d_ws, 0, 1024, stream);   // gbar + ct
  prep_kernel<<<dim3(1024), dim3(256), 0, stream>>>(hp);
  tasnet_fused<<<dim3(NBLK), dim3(NTHR), 0, stream>>>(hp);
}